// Round 5
// baseline (618.333 us; speedup 1.0000x reference)
//
#include <hip/hip_runtime.h>

// Problem constants
#define B_ 8
#define N_ 2000
#define T_ 8
#define F_ 128
#define DEG_ 8
#define H_ 4
#define G_ 64
#define PW_ 16
#define SEQ_ (N_ * T_)   // 16000
#define CB_ 32           // (b,t) slices per chunk; 2 chunks
#define QR_ 32           // GRU real steps per chunk -> 500*8 = 4000 chains
#define WARMN_ 4         // warm-up nodes (32 steps)

typedef short s8v __attribute__((ext_vector_type(8)));            // 8 bf16
typedef unsigned short u8v __attribute__((ext_vector_type(8)));   // 8 bf16 (loads)
typedef float f4v __attribute__((ext_vector_type(4)));            // MFMA acc
typedef float f2v __attribute__((ext_vector_type(2)));            // packed fp32

static __device__ __forceinline__ unsigned short f2bf(float f) {
    unsigned int u = __float_as_uint(f);
    u += 0x7FFFu + ((u >> 16) & 1u);         // RNE
    return (unsigned short)(u >> 16);
}
static __device__ __forceinline__ float bf2f(unsigned short b) {
    return __uint_as_float(((unsigned int)b) << 16);
}
static __device__ __forceinline__ s8v pack8(float4 u, float4 v) {
    s8v r;
    r[0] = (short)f2bf(u.x); r[1] = (short)f2bf(u.y);
    r[2] = (short)f2bf(u.z); r[3] = (short)f2bf(u.w);
    r[4] = (short)f2bf(v.x); r[5] = (short)f2bf(v.y);
    r[6] = (short)f2bf(v.z); r[7] = (short)f2bf(v.w);
    return r;
}

// ---------------- weight prep: W1T[h][d][f], W2T[d][k], WihB[j][k] (bf16) ----------------
__global__ void k_cvt_w(const float* __restrict__ W1, const float* __restrict__ W2,
                        const float* __restrict__ Wih,
                        unsigned short* __restrict__ W1T, unsigned short* __restrict__ W2T,
                        unsigned short* __restrict__ WihB)
{
    int idx = blockIdx.x * 256 + threadIdx.x;      // 61,440 total
    if (idx < 32768) {                              // W1 (4,128,64) -> [h][d][f]
        int h = idx >> 13, rem = idx & 8191;
        int d = rem >> 7, f = rem & 127;
        W1T[idx] = f2bf(W1[h * 8192 + f * 64 + d]);
    } else if (idx < 49152) {                       // W2 (256,64) -> [d][k]
        int i = idx - 32768;
        int d = i >> 8, k = i & 255;
        W2T[i] = f2bf(W2[k * 64 + d]);
    } else if (idx < 61440) {                       // Wih (192,64) straight
        int i = idx - 49152;
        WihB[i] = f2bf(Wih[i]);
    }
}

// ---------------- z1 GEMM (swapped: A=W1T, B=activations) + fused scores ----------------
__global__ __launch_bounds__(256) void k_mz1(
    const float* __restrict__ dyn, const unsigned short* __restrict__ W1T,
    const float* __restrict__ b1, const float* __restrict__ a1,
    unsigned short* __restrict__ z1c, float* __restrict__ s1s, float* __restrict__ s1d,
    int bt0)
{
    const int tid = threadIdx.x, w = tid >> 6, l = tid & 63;
    const int lr = l & 15, lq = l >> 4;
    const int r0 = blockIdx.x * 64 + w * 16;       // local row strip
    const int btl = r0 / 2000, n0 = r0 - btl * 2000;
    const int bt = bt0 + btl, b = bt >> 3, t = bt & 7;

    const float* Bp = dyn + (((size_t)(b * 2000) + n0 + lr) * 8 + t) * 128 + lq * 8;

    f4v acc[4][4] = {};
    #pragma unroll
    for (int ks = 0; ks < 4; ks++) {
        float4 u = *(const float4*)(Bp + ks * 32);
        float4 v = *(const float4*)(Bp + ks * 32 + 4);
        s8v bfrag = pack8(u, v);
        #pragma unroll
        for (int h = 0; h < 4; h++)
            #pragma unroll
            for (int dm = 0; dm < 4; dm++) {
                s8v a = *(const s8v*)(W1T + ((size_t)(h * 64 + dm * 16 + lr)) * 128 + lq * 8 + ks * 32);
                acc[h][dm] = __builtin_amdgcn_mfma_f32_16x16x32_bf16(a, bfrag, acc[h][dm], 0, 0, 0);
            }
    }

    const int node = n0 + lr;
    #pragma unroll
    for (int h = 0; h < 4; h++) {
        const size_t zrow = (size_t)(btl * 4 + h) * 2000 + node;
        float ps = 0.f, pd = 0.f;
        #pragma unroll
        for (int dm = 0; dm < 4; dm++) {
            const int d0 = dm * 16 + lq * 4;
            float4 bi = *(const float4*)(b1 + h * 64 + d0);
            float4 as = *(const float4*)(a1 + h * 128 + d0);
            float4 ad = *(const float4*)(a1 + h * 128 + 64 + d0);
            ushort4 st; float vv;
            vv = acc[h][dm][0] + bi.x; st.x = f2bf(vv); ps = fmaf(vv, as.x, ps); pd = fmaf(vv, ad.x, pd);
            vv = acc[h][dm][1] + bi.y; st.y = f2bf(vv); ps = fmaf(vv, as.y, ps); pd = fmaf(vv, ad.y, pd);
            vv = acc[h][dm][2] + bi.z; st.z = f2bf(vv); ps = fmaf(vv, as.z, ps); pd = fmaf(vv, ad.z, pd);
            vv = acc[h][dm][3] + bi.w; st.w = f2bf(vv); ps = fmaf(vv, as.w, ps); pd = fmaf(vv, ad.w, pd);
            *(ushort4*)(z1c + zrow * 64 + d0) = st;
        }
        ps += __shfl_xor(ps, 16); ps += __shfl_xor(ps, 32);
        pd += __shfl_xor(pd, 16); pd += __shfl_xor(pd, 32);
        if (lq == 0) { s1s[zrow] = ps; s1d[zrow] = pd; }
    }
}

// ---------------- z2 GEMM (swapped) + fused scores. K=256 ----------------
__global__ __launch_bounds__(256) void k_mz2(
    const unsigned short* __restrict__ h1c, const unsigned short* __restrict__ W2T,
    const float* __restrict__ b2, const float* __restrict__ a2,
    unsigned short* __restrict__ z2c, float* __restrict__ s2s, float* __restrict__ s2d)
{
    const int tid = threadIdx.x, w = tid >> 6, l = tid & 63;
    const int lr = l & 15, lq = l >> 4;
    const int r0 = blockIdx.x * 64 + w * 16;

    const unsigned short* Bp = h1c + (size_t)(r0 + lr) * 256 + lq * 8;

    f4v acc[4] = {};
    #pragma unroll
    for (int ks = 0; ks < 8; ks++) {
        s8v bfrag = *(const s8v*)(Bp + ks * 32);
        #pragma unroll
        for (int dm = 0; dm < 4; dm++) {
            s8v a = *(const s8v*)(W2T + ((size_t)(dm * 16 + lr)) * 256 + lq * 8 + ks * 32);
            acc[dm] = __builtin_amdgcn_mfma_f32_16x16x32_bf16(a, bfrag, acc[dm], 0, 0, 0);
        }
    }

    const int node = r0 + lr;
    float ps = 0.f, pd = 0.f;
    #pragma unroll
    for (int dm = 0; dm < 4; dm++) {
        const int d0 = dm * 16 + lq * 4;
        float4 bi = *(const float4*)(b2 + d0);
        float4 as = *(const float4*)(a2 + d0);
        float4 ad = *(const float4*)(a2 + 64 + d0);
        ushort4 st; float vv;
        vv = acc[dm][0] + bi.x; st.x = f2bf(vv); ps = fmaf(vv, as.x, ps); pd = fmaf(vv, ad.x, pd);
        vv = acc[dm][1] + bi.y; st.y = f2bf(vv); ps = fmaf(vv, as.y, ps); pd = fmaf(vv, ad.y, pd);
        vv = acc[dm][2] + bi.z; st.z = f2bf(vv); ps = fmaf(vv, as.z, ps); pd = fmaf(vv, ad.z, pd);
        vv = acc[dm][3] + bi.w; st.w = f2bf(vv); ps = fmaf(vv, as.w, ps); pd = fmaf(vv, ad.w, pd);
        *(ushort4*)(z2c + (size_t)node * 64 + d0) = st;
    }
    ps += __shfl_xor(ps, 16); ps += __shfl_xor(ps, 32);
    pd += __shfl_xor(pd, 16); pd += __shfl_xor(pd, 32);
    if (lq == 0) { s2s[node] = ps; s2d[node] = pd; }
}

// ---------------- gi GEMM -> node-blocked gib2[b][n][c][t] (8B stores) ----------------
__global__ __launch_bounds__(256) void k_mgi(
    const unsigned short* __restrict__ h2b, const unsigned short* __restrict__ WihB,
    const float* __restrict__ bih, unsigned short* __restrict__ gib2)
{
    const int tid = threadIdx.x, w = tid >> 6, l = tid & 63;
    const int lr = l & 15, lq = l >> 4;
    const int r0 = blockIdx.x * 64 + w * 16;
    const int col0 = blockIdx.y * 64;

    const int rA = r0 + lr;
    const int bA = rA / 16000;
    const int remA = rA - bA * 16000;
    const int nAr = remA >> 3, tA = remA & 7;
    const unsigned short* Ab = h2b + ((size_t)((bA * 8 + tA) * 2000) + nAr) * 64 + lq * 8;

    f4v acc[4] = {};
    #pragma unroll
    for (int ks = 0; ks < 2; ks++) {
        s8v a = *(const s8v*)(Ab + ks * 32);
        #pragma unroll
        for (int nt = 0; nt < 4; nt++) {
            s8v bfr = *(const s8v*)(WihB + ((size_t)(col0 + nt * 16 + lr)) * 64 + lq * 8 + ks * 32);
            acc[nt] = __builtin_amdgcn_mfma_f32_16x16x32_bf16(a, bfr, acc[nt], 0, 0, 0);
        }
    }
    // C rows: rr = r0 + lq*4 + rg  (4 consecutive t within one node; tO in {0,4})
    const int rrb = r0 + lq * 4;
    const int bO = rrb / 16000;
    const int remO = rrb - bO * 16000;
    const int nO = remO >> 3, tO = remO & 7;
    #pragma unroll
    for (int nt = 0; nt < 4; nt++) {
        int cc = col0 + nt * 16 + lr;
        float bias = bih[cc];
        ushort4 st;
        st.x = f2bf(acc[nt][0] + bias); st.y = f2bf(acc[nt][1] + bias);
        st.z = f2bf(acc[nt][2] + bias); st.w = f2bf(acc[nt][3] + bias);
        *(ushort4*)(gib2 + (((size_t)(bO * 2000 + nO)) * 192 + cc) * 8 + tO) = st;
    }
}

// ---------------- edge softmax + aggregation + ELU, 4 rows per wave ----------------
__global__ void k_agg(const unsigned short* __restrict__ z, const float* __restrict__ ssrc,
                      const float* __restrict__ sdst, const float* __restrict__ ab,
                      const int* __restrict__ src, unsigned short* __restrict__ out,
                      int Hn, int outStride, int bt0base)
{
    const int wv = threadIdx.x >> 6, lane = threadIdx.x & 63;
    const int rbase = blockIdx.x * 16 + wv * 4;

    int siA[4][8]; float ssA[4][8]; unsigned short zsA[4][8];
    float sdA[4]; int nA[4], bthA[4];
    #pragma unroll
    for (int rw = 0; rw < 4; rw++) {
        int row = rbase + rw;
        int bth = row / N_; int n = row - bth * N_;
        nA[rw] = n; bthA[rw] = bth;
        int4 s0 = *(const int4*)(src + n * 8);
        int4 s1 = *(const int4*)(src + n * 8 + 4);
        siA[rw][0] = s0.x; siA[rw][1] = s0.y; siA[rw][2] = s0.z; siA[rw][3] = s0.w;
        siA[rw][4] = s1.x; siA[rw][5] = s1.y; siA[rw][6] = s1.z; siA[rw][7] = s1.w;
    }
    #pragma unroll
    for (int rw = 0; rw < 4; rw++)
        #pragma unroll
        for (int k = 0; k < 8; k++)
            ssA[rw][k] = ssrc[(size_t)bthA[rw] * N_ + siA[rw][k]];
    #pragma unroll
    for (int rw = 0; rw < 4; rw++)
        #pragma unroll
        for (int k = 0; k < 8; k++)
            zsA[rw][k] = z[((size_t)bthA[rw] * N_ + siA[rw][k]) * 64 + lane];
    #pragma unroll
    for (int rw = 0; rw < 4; rw++)
        sdA[rw] = sdst[rbase + rw] + ab[bthA[rw] % Hn];

    #pragma unroll
    for (int rw = 0; rw < 4; rw++) {
        float e[8];
        #pragma unroll
        for (int k = 0; k < 8; k++) {
            float ev = ssA[rw][k] + sdA[rw];
            e[k] = ev > 0.f ? ev : 0.01f * ev;
        }
        float m = e[0];
        #pragma unroll
        for (int k = 1; k < 8; k++) m = fmaxf(m, e[k]);
        float sum = 0.f;
        #pragma unroll
        for (int k = 0; k < 8; k++) { e[k] = __expf(e[k] - m); sum += e[k]; }
        float inv = 1.f / sum;
        float acc = 0.f;
        #pragma unroll
        for (int k = 0; k < 8; k++) acc = fmaf(e[k], bf2f(zsA[rw][k]), acc);
        acc *= inv;
        acc = acc > 0.f ? acc : (__expf(acc) - 1.f);
        int h = bthA[rw] % Hn, btl = bthA[rw] / Hn;
        out[((size_t)(bt0base + btl) * N_ + nA[rw]) * outStride + h * 64 + lane] = f2bf(acc);
    }
}

// ---------------- chunked GRU: node-blocked gi (b128 loads), 4000 chains ----------------
__global__ __launch_bounds__(64, 1) void k_gru(
    const unsigned short* __restrict__ gib2, const float* __restrict__ Whh,
    const float* __restrict__ bhh, const float* __restrict__ h0,
    float* __restrict__ hloc)
{
    const int c = blockIdx.x;
    const int q = c >> 3, b = c & 7;
    const int j = threadIdx.x;

    const f2v* Wr = (const f2v*)(Whh + (size_t)j * 64);
    const f2v* Wz = (const f2v*)(Whh + (size_t)(64 + j) * 64);
    const f2v* Wn = (const f2v*)(Whh + (size_t)(128 + j) * 64);
    f2v wr2[32], wz2[32], wn2[32];
    #pragma unroll
    for (int k = 0; k < 32; k++) { wr2[k] = Wr[k]; wz2[k] = Wz[k]; wn2[k] = Wn[k]; }
    const float bhr = bhh[j], bhz = bhh[64 + j], bhn = bhh[128 + j];

    int nd0 = q * 4 - WARMN_; if (nd0 < 0) nd0 = 0;
    const int ndEnd = q * 4 + 4;
    const int ndReal = q * 4;

    __shared__ float hb[2][64];
    float hj = (nd0 == 0) ? h0[b * 64 + j] : 0.f;
    hb[0][j] = hj;
    __syncthreads();

    const unsigned short* gp = gib2 + (((size_t)(b * 2000) + nd0) * 192 + j) * 8;
    u8v cr = *(const u8v*)(gp);
    u8v cz = *(const u8v*)(gp + 512);
    u8v cn = *(const u8v*)(gp + 1024);

    int p = 0;
    for (int nd = nd0; nd < ndEnd; nd++) {
        const unsigned short* gq = gp + 1536;
        u8v xr = {}, xz = {}, xn = {};
        if (nd + 1 < ndEnd) {
            xr = *(const u8v*)(gq);
            xz = *(const u8v*)(gq + 512);
            xn = *(const u8v*)(gq + 1024);
        }
        #pragma unroll
        for (int ts = 0; ts < 8; ts++) {
            float grA = bf2f(cr[ts]), gzA = bf2f(cz[ts]), gnA = bf2f(cn[ts]);

            f2v arA = {bhr, 0.f}, arB = {0.f, 0.f};
            f2v azA = {bhz, 0.f}, azB = {0.f, 0.f};
            f2v anA = {bhn, 0.f}, anB = {0.f, 0.f};
            const float4* h4 = (const float4*)hb[p];
            #pragma unroll
            for (int k8 = 0; k8 < 8; k8++) {
                float4 ha = h4[2 * k8], hc = h4[2 * k8 + 1];
                f2v h01 = {ha.x, ha.y}, h23 = {ha.z, ha.w};
                f2v h45 = {hc.x, hc.y}, h67 = {hc.z, hc.w};
                int kb = 4 * k8;
                arA = __builtin_elementwise_fma(h01, wr2[kb],     arA);
                arB = __builtin_elementwise_fma(h23, wr2[kb + 1], arB);
                arA = __builtin_elementwise_fma(h45, wr2[kb + 2], arA);
                arB = __builtin_elementwise_fma(h67, wr2[kb + 3], arB);
                azA = __builtin_elementwise_fma(h01, wz2[kb],     azA);
                azB = __builtin_elementwise_fma(h23, wz2[kb + 1], azB);
                azA = __builtin_elementwise_fma(h45, wz2[kb + 2], azA);
                azB = __builtin_elementwise_fma(h67, wz2[kb + 3], azB);
                anA = __builtin_elementwise_fma(h01, wn2[kb],     anA);
                anB = __builtin_elementwise_fma(h23, wn2[kb + 1], anB);
                anA = __builtin_elementwise_fma(h45, wn2[kb + 2], anA);
                anB = __builtin_elementwise_fma(h67, wn2[kb + 3], anB);
            }
            float ar = arA.x + arA.y + arB.x + arB.y;
            float az = azA.x + azA.y + azB.x + azB.y;
            float an = anA.x + anA.y + anB.x + anB.y;
            float r  = 1.f / (1.f + __expf(-(grA + ar)));
            float zg = 1.f / (1.f + __expf(-(gzA + az)));
            float tt = gnA + r * an;
            float nn = 1.f - 2.f / (__expf(2.f * tt) + 1.f);
            hj = (1.f - zg) * nn + zg * hj;

            if (ts == 7 && nd >= ndReal)
                hloc[((size_t)nd * B_ + b) * 64 + j] = hj;

            p ^= 1;
            hb[p][j] = hj;
            __syncthreads();
        }
        cr = xr; cz = xz; cn = xn;
        gp = gq;
    }
}

// ---------------- final projection ----------------
__global__ void k_proj(const float* __restrict__ hloc, const float* __restrict__ Wp,
                       const float* __restrict__ bp, float* __restrict__ out)
{
    int idx = blockIdx.x * 256 + threadIdx.x;   // 256000 total
    int p = idx & 15;
    int b = (idx >> 4) & 7;
    int n = idx >> 7;
    const float* hr = hloc + ((size_t)n * B_ + b) * 64;
    float acc = bp[p];
    #pragma unroll
    for (int jj = 0; jj < 64; jj++) acc = fmaf(hr[jj], Wp[jj * 16 + p], acc);
    out[((size_t)b * N_ + n) * PW_ + p] = acc;
}

extern "C" void kernel_launch(void* const* d_in, const int* in_sizes, int n_in,
                              void* d_out, int out_size, void* d_ws, size_t ws_size,
                              hipStream_t stream) {
    const float* dyn  = (const float*)d_in[0];
    const float* h0   = (const float*)d_in[1];
    const int*   src  = (const int*)  d_in[2];
    const float* W1   = (const float*)d_in[3];
    const float* b1   = (const float*)d_in[4];
    const float* a1   = (const float*)d_in[5];
    const float* a1b  = (const float*)d_in[6];
    const float* W2   = (const float*)d_in[7];
    const float* b2   = (const float*)d_in[8];
    const float* a2   = (const float*)d_in[9];
    const float* a2b  = (const float*)d_in[10];
    const float* Wih  = (const float*)d_in[11];
    const float* Whh  = (const float*)d_in[12];
    const float* bih  = (const float*)d_in[13];
    const float* bhh  = (const float*)d_in[14];
    const float* Wp   = (const float*)d_in[15];
    const float* bp   = (const float*)d_in[16];
    float* out = (float*)d_out;

    // Workspace (bytes), peak ~96.9 MB (known-good)
    char* w = (char*)d_ws;
    unsigned short* z1c  = (unsigned short*)(w);                 // 32,768,000
    unsigned short* h1c  = (unsigned short*)(w + 32768000);      // 32,768,000
    unsigned short* z2c  = (unsigned short*)(w + 65536000);      //  8,192,000
    float*          s1s  = (float*)        (w + 73728000);       //  1,024,000
    float*          s1d  = (float*)        (w + 74752000);       //  1,024,000
    float*          s2s  = (float*)        (w + 75776000);       //    256,000
    float*          s2d  = (float*)        (w + 76032000);       //    256,000
    unsigned short* gib2 = (unsigned short*)(w);                 // 49,152,000 (after chunks)
    unsigned short* h2b  = (unsigned short*)(w + 76288000);      // 16,384,000
    unsigned short* W1T  = (unsigned short*)(w + 92672000);      //     65,536
    unsigned short* W2T  = (unsigned short*)(w + 92737536);      //     32,768
    unsigned short* WihB = (unsigned short*)(w + 92770304);      //     24,576
    float*          hloc = (float*)        (w + 92794880);       //  4,096,000

    k_cvt_w<<<240, 256, 0, stream>>>(W1, W2, Wih, W1T, W2T, WihB);

    for (int c = 0; c < 64 / CB_; c++) {
        int bt0 = c * CB_;
        k_mz1<<<1000, 256, 0, stream>>>(dyn, W1T, b1, a1, z1c, s1s, s1d, bt0);
        k_agg<<<16000, 256, 0, stream>>>(z1c, s1s, s1d, a1b, src, h1c, H_, 256, 0);
        k_mz2<<<1000, 256, 0, stream>>>(h1c, W2T, b2, a2, z2c, s2s, s2d);
        k_agg<<<4000, 256, 0, stream>>>(z2c, s2s, s2d, a2b, src, h2b, 1, 64, bt0);
    }
    k_mgi<<<dim3(2000, 3), 256, 0, stream>>>(h2b, WihB, bih, gib2);
    k_gru<<<4000, 64, 0, stream>>>(gib2, Whh, bhh, h0, hloc);
    k_proj<<<1000, 256, 0, stream>>>(hloc, Wp, bp, out);
}

// Round 6
// 565.306 us; speedup vs baseline: 1.0938x; 1.0938x over previous
//
#include <hip/hip_runtime.h>

// Problem constants
#define B_ 8
#define N_ 2000
#define T_ 8
#define F_ 128
#define DEG_ 8
#define H_ 4
#define G_ 64
#define PW_ 16
#define SEQ_ (N_ * T_)   // 16000
#define CB_ 32           // (b,t) slices per chunk; 2 chunks

typedef short s8v __attribute__((ext_vector_type(8)));            // 8 bf16
typedef unsigned short u8v __attribute__((ext_vector_type(8)));   // 8 bf16 (loads)
typedef float f4v __attribute__((ext_vector_type(4)));            // MFMA acc

static __device__ __forceinline__ unsigned short f2bf(float f) {
    unsigned int u = __float_as_uint(f);
    u += 0x7FFFu + ((u >> 16) & 1u);         // RNE
    return (unsigned short)(u >> 16);
}
static __device__ __forceinline__ float bf2f(unsigned short b) {
    return __uint_as_float(((unsigned int)b) << 16);
}
static __device__ __forceinline__ s8v pack8(float4 u, float4 v) {
    s8v r;
    r[0] = (short)f2bf(u.x); r[1] = (short)f2bf(u.y);
    r[2] = (short)f2bf(u.z); r[3] = (short)f2bf(u.w);
    r[4] = (short)f2bf(v.x); r[5] = (short)f2bf(v.y);
    r[6] = (short)f2bf(v.z); r[7] = (short)f2bf(v.w);
    return r;
}

// ---------------- weight prep: W1T[h][d][f], W2T[d][k], WihB[j][k], WhhB (bf16) ----------------
__global__ void k_cvt_w(const float* __restrict__ W1, const float* __restrict__ W2,
                        const float* __restrict__ Wih, const float* __restrict__ Whh,
                        unsigned short* __restrict__ W1T, unsigned short* __restrict__ W2T,
                        unsigned short* __restrict__ WihB, unsigned short* __restrict__ WhhB)
{
    int idx = blockIdx.x * 256 + threadIdx.x;      // 73,728 total
    if (idx < 32768) {                              // W1 (4,128,64) -> [h][d][f]
        int h = idx >> 13, rem = idx & 8191;
        int d = rem >> 7, f = rem & 127;
        W1T[idx] = f2bf(W1[h * 8192 + f * 64 + d]);
    } else if (idx < 49152) {                       // W2 (256,64) -> [d][k]
        int i = idx - 32768;
        int d = i >> 8, k = i & 255;
        W2T[i] = f2bf(W2[k * 64 + d]);
    } else if (idx < 61440) {                       // Wih (192,64) straight
        int i = idx - 49152;
        WihB[i] = f2bf(Wih[i]);
    } else if (idx < 73728) {                       // Whh (192,64) straight
        int i = idx - 61440;
        WhhB[i] = f2bf(Whh[i]);
    }
}

// ---------------- z1 GEMM (A=W1T, B=activations) + fused scores ----------------
__global__ __launch_bounds__(256) void k_mz1(
    const float* __restrict__ dyn, const unsigned short* __restrict__ W1T,
    const float* __restrict__ b1, const float* __restrict__ a1,
    unsigned short* __restrict__ z1c, float* __restrict__ s1s, float* __restrict__ s1d,
    int bt0)
{
    const int tid = threadIdx.x, w = tid >> 6, l = tid & 63;
    const int lr = l & 15, lq = l >> 4;
    const int r0 = blockIdx.x * 64 + w * 16;       // local row strip
    const int btl = r0 / 2000, n0 = r0 - btl * 2000;
    const int bt = bt0 + btl, b = bt >> 3, t = bt & 7;

    const float* Bp = dyn + (((size_t)(b * 2000) + n0 + lr) * 8 + t) * 128 + lq * 8;

    f4v acc[4][4] = {};
    #pragma unroll
    for (int ks = 0; ks < 4; ks++) {
        float4 u = *(const float4*)(Bp + ks * 32);
        float4 v = *(const float4*)(Bp + ks * 32 + 4);
        s8v bfrag = pack8(u, v);
        #pragma unroll
        for (int h = 0; h < 4; h++)
            #pragma unroll
            for (int dm = 0; dm < 4; dm++) {
                s8v a = *(const s8v*)(W1T + ((size_t)(h * 64 + dm * 16 + lr)) * 128 + lq * 8 + ks * 32);
                acc[h][dm] = __builtin_amdgcn_mfma_f32_16x16x32_bf16(a, bfrag, acc[h][dm], 0, 0, 0);
            }
    }

    const int node = n0 + lr;
    #pragma unroll
    for (int h = 0; h < 4; h++) {
        const size_t zrow = (size_t)(btl * 4 + h) * 2000 + node;
        float ps = 0.f, pd = 0.f;
        #pragma unroll
        for (int dm = 0; dm < 4; dm++) {
            const int d0 = dm * 16 + lq * 4;
            float4 bi = *(const float4*)(b1 + h * 64 + d0);
            float4 as = *(const float4*)(a1 + h * 128 + d0);
            float4 ad = *(const float4*)(a1 + h * 128 + 64 + d0);
            ushort4 st; float vv;
            vv = acc[h][dm][0] + bi.x; st.x = f2bf(vv); ps = fmaf(vv, as.x, ps); pd = fmaf(vv, ad.x, pd);
            vv = acc[h][dm][1] + bi.y; st.y = f2bf(vv); ps = fmaf(vv, as.y, ps); pd = fmaf(vv, ad.y, pd);
            vv = acc[h][dm][2] + bi.z; st.z = f2bf(vv); ps = fmaf(vv, as.z, ps); pd = fmaf(vv, ad.z, pd);
            vv = acc[h][dm][3] + bi.w; st.w = f2bf(vv); ps = fmaf(vv, as.w, ps); pd = fmaf(vv, ad.w, pd);
            *(ushort4*)(z1c + zrow * 64 + d0) = st;
        }
        ps += __shfl_xor(ps, 16); ps += __shfl_xor(ps, 32);
        pd += __shfl_xor(pd, 16); pd += __shfl_xor(pd, 32);
        if (lq == 0) { s1s[zrow] = ps; s1d[zrow] = pd; }
    }
}

// ---------------- z2 GEMM + fused scores. K=256 ----------------
__global__ __launch_bounds__(256) void k_mz2(
    const unsigned short* __restrict__ h1c, const unsigned short* __restrict__ W2T,
    const float* __restrict__ b2, const float* __restrict__ a2,
    unsigned short* __restrict__ z2c, float* __restrict__ s2s, float* __restrict__ s2d)
{
    const int tid = threadIdx.x, w = tid >> 6, l = tid & 63;
    const int lr = l & 15, lq = l >> 4;
    const int r0 = blockIdx.x * 64 + w * 16;

    const unsigned short* Bp = h1c + (size_t)(r0 + lr) * 256 + lq * 8;

    f4v acc[4] = {};
    #pragma unroll
    for (int ks = 0; ks < 8; ks++) {
        s8v bfrag = *(const s8v*)(Bp + ks * 32);
        #pragma unroll
        for (int dm = 0; dm < 4; dm++) {
            s8v a = *(const s8v*)(W2T + ((size_t)(dm * 16 + lr)) * 256 + lq * 8 + ks * 32);
            acc[dm] = __builtin_amdgcn_mfma_f32_16x16x32_bf16(a, bfrag, acc[dm], 0, 0, 0);
        }
    }

    const int node = r0 + lr;
    float ps = 0.f, pd = 0.f;
    #pragma unroll
    for (int dm = 0; dm < 4; dm++) {
        const int d0 = dm * 16 + lq * 4;
        float4 bi = *(const float4*)(b2 + d0);
        float4 as = *(const float4*)(a2 + d0);
        float4 ad = *(const float4*)(a2 + 64 + d0);
        ushort4 st; float vv;
        vv = acc[dm][0] + bi.x; st.x = f2bf(vv); ps = fmaf(vv, as.x, ps); pd = fmaf(vv, ad.x, pd);
        vv = acc[dm][1] + bi.y; st.y = f2bf(vv); ps = fmaf(vv, as.y, ps); pd = fmaf(vv, ad.y, pd);
        vv = acc[dm][2] + bi.z; st.z = f2bf(vv); ps = fmaf(vv, as.z, ps); pd = fmaf(vv, ad.z, pd);
        vv = acc[dm][3] + bi.w; st.w = f2bf(vv); ps = fmaf(vv, as.w, ps); pd = fmaf(vv, ad.w, pd);
        *(ushort4*)(z2c + (size_t)node * 64 + d0) = st;
    }
    ps += __shfl_xor(ps, 16); ps += __shfl_xor(ps, 32);
    pd += __shfl_xor(pd, 16); pd += __shfl_xor(pd, 32);
    if (lq == 0) { s2s[node] = ps; s2d[node] = pd; }
}

// ---------------- gi GEMM -> node-blocked gib2[b][n][c][t] ----------------
__global__ __launch_bounds__(256) void k_mgi(
    const unsigned short* __restrict__ h2b, const unsigned short* __restrict__ WihB,
    const float* __restrict__ bih, unsigned short* __restrict__ gib2)
{
    const int tid = threadIdx.x, w = tid >> 6, l = tid & 63;
    const int lr = l & 15, lq = l >> 4;
    const int r0 = blockIdx.x * 64 + w * 16;
    const int col0 = blockIdx.y * 64;

    const int rA = r0 + lr;
    const int bA = rA / 16000;
    const int remA = rA - bA * 16000;
    const int nAr = remA >> 3, tA = remA & 7;
    const unsigned short* Ab = h2b + ((size_t)((bA * 8 + tA) * 2000) + nAr) * 64 + lq * 8;

    f4v acc[4] = {};
    #pragma unroll
    for (int ks = 0; ks < 2; ks++) {
        s8v a = *(const s8v*)(Ab + ks * 32);
        #pragma unroll
        for (int nt = 0; nt < 4; nt++) {
            s8v bfr = *(const s8v*)(WihB + ((size_t)(col0 + nt * 16 + lr)) * 64 + lq * 8 + ks * 32);
            acc[nt] = __builtin_amdgcn_mfma_f32_16x16x32_bf16(a, bfr, acc[nt], 0, 0, 0);
        }
    }
    const int rrb = r0 + lq * 4;
    const int bO = rrb / 16000;
    const int remO = rrb - bO * 16000;
    const int nO = remO >> 3, tO = remO & 7;
    #pragma unroll
    for (int nt = 0; nt < 4; nt++) {
        int cc = col0 + nt * 16 + lr;
        float bias = bih[cc];
        ushort4 st;
        st.x = f2bf(acc[nt][0] + bias); st.y = f2bf(acc[nt][1] + bias);
        st.z = f2bf(acc[nt][2] + bias); st.w = f2bf(acc[nt][3] + bias);
        *(ushort4*)(gib2 + (((size_t)(bO * 2000 + nO)) * 192 + cc) * 8 + tO) = st;
    }
}

// ---------------- edge softmax + aggregation + ELU, 4 rows per wave ----------------
__global__ void k_agg(const unsigned short* __restrict__ z, const float* __restrict__ ssrc,
                      const float* __restrict__ sdst, const float* __restrict__ ab,
                      const int* __restrict__ src, unsigned short* __restrict__ out,
                      int Hn, int outStride, int bt0base)
{
    const int wv = threadIdx.x >> 6, lane = threadIdx.x & 63;
    const int rbase = blockIdx.x * 16 + wv * 4;

    int siA[4][8]; float ssA[4][8]; unsigned short zsA[4][8];
    float sdA[4]; int nA[4], bthA[4];
    #pragma unroll
    for (int rw = 0; rw < 4; rw++) {
        int row = rbase + rw;
        int bth = row / N_; int n = row - bth * N_;
        nA[rw] = n; bthA[rw] = bth;
        int4 s0 = *(const int4*)(src + n * 8);
        int4 s1 = *(const int4*)(src + n * 8 + 4);
        siA[rw][0] = s0.x; siA[rw][1] = s0.y; siA[rw][2] = s0.z; siA[rw][3] = s0.w;
        siA[rw][4] = s1.x; siA[rw][5] = s1.y; siA[rw][6] = s1.z; siA[rw][7] = s1.w;
    }
    #pragma unroll
    for (int rw = 0; rw < 4; rw++)
        #pragma unroll
        for (int k = 0; k < 8; k++)
            ssA[rw][k] = ssrc[(size_t)bthA[rw] * N_ + siA[rw][k]];
    #pragma unroll
    for (int rw = 0; rw < 4; rw++)
        #pragma unroll
        for (int k = 0; k < 8; k++)
            zsA[rw][k] = z[((size_t)bthA[rw] * N_ + siA[rw][k]) * 64 + lane];
    #pragma unroll
    for (int rw = 0; rw < 4; rw++)
        sdA[rw] = sdst[rbase + rw] + ab[bthA[rw] % Hn];

    #pragma unroll
    for (int rw = 0; rw < 4; rw++) {
        float e[8];
        #pragma unroll
        for (int k = 0; k < 8; k++) {
            float ev = ssA[rw][k] + sdA[rw];
            e[k] = ev > 0.f ? ev : 0.01f * ev;
        }
        float m = e[0];
        #pragma unroll
        for (int k = 1; k < 8; k++) m = fmaxf(m, e[k]);
        float sum = 0.f;
        #pragma unroll
        for (int k = 0; k < 8; k++) { e[k] = __expf(e[k] - m); sum += e[k]; }
        float inv = 1.f / sum;
        float acc = 0.f;
        #pragma unroll
        for (int k = 0; k < 8; k++) acc = fmaf(e[k], bf2f(zsA[rw][k]), acc);
        acc *= inv;
        acc = acc > 0.f ? acc : (__expf(acc) - 1.f);
        int h = bthA[rw] % Hn, btl = bthA[rw] / Hn;
        out[((size_t)(bt0base + btl) * N_ + nA[rw]) * outStride + h * 64 + lane] = f2bf(acc);
    }
}

// ---------------- MFMA GRU: 500 blocks x 4 waves, all 8 batches per block ----------------
// Block q: warm nodes [4q-4,4q), real [4q,4q+4). Per step: Whh(192x64)@H(64x8) via
// 6 MFMA/wave (wave w owns j in [16w,16w+16)). H in triple-buffered LDS [batch][k],
// 1 barrier/step. gi per node prefetched (12 x u8v). h_prev in registers.
__global__ __launch_bounds__(256) void k_gru(
    const unsigned short* __restrict__ gib2, const unsigned short* __restrict__ WhhB,
    const float* __restrict__ bhh, const float* __restrict__ h0,
    float* __restrict__ hloc)
{
    const int q = blockIdx.x;
    const int tid = threadIdx.x;
    const int w = tid >> 6, l = tid & 63;
    const int lr = l & 15, lq = l >> 4;
    const int j0 = w * 16 + lq * 4;      // first j of this lane's 4 outputs
    const int bb = lr & 7;               // batch (lanes lr>=8 duplicate, unused)

    __shared__ unsigned short hbuf[3][16][72];   // [buf][batch][k] padded to 72

    {   // zero-init all buffers (also cols 8..15 stay 0 forever)
        unsigned int* p = (unsigned int*)hbuf;
        #pragma unroll 1
        for (int i = tid; i < 3 * 16 * 72 / 2; i += 256) p[i] = 0u;
    }
    __syncthreads();

    // A-frags: row = gate*64 + (16w + lr), k = kt*32 + lq*8 + i
    const int jrow = w * 16 + lr;
    s8v wR0 = *(const s8v*)(WhhB + (size_t)jrow * 64 + lq * 8);
    s8v wR1 = *(const s8v*)(WhhB + (size_t)jrow * 64 + 32 + lq * 8);
    s8v wZ0 = *(const s8v*)(WhhB + (size_t)(64 + jrow) * 64 + lq * 8);
    s8v wZ1 = *(const s8v*)(WhhB + (size_t)(64 + jrow) * 64 + 32 + lq * 8);
    s8v wN0 = *(const s8v*)(WhhB + (size_t)(128 + jrow) * 64 + lq * 8);
    s8v wN1 = *(const s8v*)(WhhB + (size_t)(128 + jrow) * 64 + 32 + lq * 8);

    float4 t4;
    t4 = *(const float4*)(bhh + j0);        float bhr_[4] = {t4.x, t4.y, t4.z, t4.w};
    t4 = *(const float4*)(bhh + 64 + j0);   float bhz_[4] = {t4.x, t4.y, t4.z, t4.w};
    t4 = *(const float4*)(bhh + 128 + j0);  float bhn_[4] = {t4.x, t4.y, t4.z, t4.w};

    float hp[4] = {0.f, 0.f, 0.f, 0.f};
    if (q == 0 && lr < 8) {
        float4 h04 = *(const float4*)(h0 + lr * 64 + j0);
        hp[0] = h04.x; hp[1] = h04.y; hp[2] = h04.z; hp[3] = h04.w;
        ushort4 st;
        st.x = f2bf(hp[0]); st.y = f2bf(hp[1]); st.z = f2bf(hp[2]); st.w = f2bf(hp[3]);
        *(ushort4*)&hbuf[0][lr][j0] = st;
    }
    __syncthreads();

    int nd0 = q * 4 - 4; if (nd0 < 0) nd0 = 0;
    const int ndEnd = q * 4 + 4;
    const int ndReal = q * 4;

    const unsigned short* gbase = gib2 + ((size_t)bb * 2000) * 192 * 8;
    u8v cRv[4], cZv[4], cNv[4];
    #pragma unroll
    for (int rg = 0; rg < 4; rg++) {
        cRv[rg] = *(const u8v*)(gbase + (((size_t)nd0 * 192 + j0 + rg)) * 8);
        cZv[rg] = *(const u8v*)(gbase + (((size_t)nd0 * 192 + 64 + j0 + rg)) * 8);
        cNv[rg] = *(const u8v*)(gbase + (((size_t)nd0 * 192 + 128 + j0 + rg)) * 8);
    }

    int sb = 0;
    for (int nd = nd0; nd < ndEnd; ++nd) {
        u8v nRv[4] = {}, nZv[4] = {}, nNv[4] = {};
        if (nd + 1 < ndEnd) {
            #pragma unroll
            for (int rg = 0; rg < 4; rg++) {
                nRv[rg] = *(const u8v*)(gbase + (((size_t)(nd + 1) * 192 + j0 + rg)) * 8);
                nZv[rg] = *(const u8v*)(gbase + (((size_t)(nd + 1) * 192 + 64 + j0 + rg)) * 8);
                nNv[rg] = *(const u8v*)(gbase + (((size_t)(nd + 1) * 192 + 128 + j0 + rg)) * 8);
            }
        }
        #pragma unroll
        for (int ts = 0; ts < 8; ts++) {
            const unsigned short* hbp = &hbuf[sb][lr][0];
            s8v hb0 = *(const s8v*)(hbp + lq * 8);         // k in [0,32)
            s8v hb1 = *(const s8v*)(hbp + 32 + lq * 8);    // k in [32,64)

            f4v aR = {}, aZ = {}, aN = {};
            aR = __builtin_amdgcn_mfma_f32_16x16x32_bf16(wR0, hb0, aR, 0, 0, 0);
            aR = __builtin_amdgcn_mfma_f32_16x16x32_bf16(wR1, hb1, aR, 0, 0, 0);
            aZ = __builtin_amdgcn_mfma_f32_16x16x32_bf16(wZ0, hb0, aZ, 0, 0, 0);
            aZ = __builtin_amdgcn_mfma_f32_16x16x32_bf16(wZ1, hb1, aZ, 0, 0, 0);
            aN = __builtin_amdgcn_mfma_f32_16x16x32_bf16(wN0, hb0, aN, 0, 0, 0);
            aN = __builtin_amdgcn_mfma_f32_16x16x32_bf16(wN1, hb1, aN, 0, 0, 0);

            #pragma unroll
            for (int rg = 0; rg < 4; rg++) {
                float gr = bf2f((unsigned short)cRv[rg][ts]);
                float gz = bf2f((unsigned short)cZv[rg][ts]);
                float gn = bf2f((unsigned short)cNv[rg][ts]);
                float rr = 1.f / (1.f + __expf(-(gr + aR[rg] + bhr_[rg])));
                float zz = 1.f / (1.f + __expf(-(gz + aZ[rg] + bhz_[rg])));
                float tn = gn + rr * (aN[rg] + bhn_[rg]);
                float nn = 1.f - 2.f / (__expf(2.f * tn) + 1.f);
                hp[rg] = (1.f - zz) * nn + zz * hp[rg];
            }

            int nsb = sb + 1; if (nsb == 3) nsb = 0;
            if (lr < 8) {
                ushort4 st;
                st.x = f2bf(hp[0]); st.y = f2bf(hp[1]);
                st.z = f2bf(hp[2]); st.w = f2bf(hp[3]);
                *(ushort4*)&hbuf[nsb][lr][j0] = st;
                if (ts == 7 && nd >= ndReal) {
                    float4 o; o.x = hp[0]; o.y = hp[1]; o.z = hp[2]; o.w = hp[3];
                    *(float4*)(hloc + ((size_t)(nd * 8 + lr) * 64 + j0)) = o;
                }
            }
            __syncthreads();
            sb = nsb;
        }
        #pragma unroll
        for (int rg = 0; rg < 4; rg++) {
            cRv[rg] = nRv[rg]; cZv[rg] = nZv[rg]; cNv[rg] = nNv[rg];
        }
    }
}

// ---------------- final projection ----------------
__global__ void k_proj(const float* __restrict__ hloc, const float* __restrict__ Wp,
                       const float* __restrict__ bp, float* __restrict__ out)
{
    int idx = blockIdx.x * 256 + threadIdx.x;   // 256000 total
    int p = idx & 15;
    int b = (idx >> 4) & 7;
    int n = idx >> 7;
    const float* hr = hloc + ((size_t)n * B_ + b) * 64;
    float acc = bp[p];
    #pragma unroll
    for (int jj = 0; jj < 64; jj++) acc = fmaf(hr[jj], Wp[jj * 16 + p], acc);
    out[((size_t)b * N_ + n) * PW_ + p] = acc;
}

extern "C" void kernel_launch(void* const* d_in, const int* in_sizes, int n_in,
                              void* d_out, int out_size, void* d_ws, size_t ws_size,
                              hipStream_t stream) {
    const float* dyn  = (const float*)d_in[0];
    const float* h0   = (const float*)d_in[1];
    const int*   src  = (const int*)  d_in[2];
    const float* W1   = (const float*)d_in[3];
    const float* b1   = (const float*)d_in[4];
    const float* a1   = (const float*)d_in[5];
    const float* a1b  = (const float*)d_in[6];
    const float* W2   = (const float*)d_in[7];
    const float* b2   = (const float*)d_in[8];
    const float* a2   = (const float*)d_in[9];
    const float* a2b  = (const float*)d_in[10];
    const float* Wih  = (const float*)d_in[11];
    const float* Whh  = (const float*)d_in[12];
    const float* bih  = (const float*)d_in[13];
    const float* bhh  = (const float*)d_in[14];
    const float* Wp   = (const float*)d_in[15];
    const float* bp   = (const float*)d_in[16];
    float* out = (float*)d_out;

    // Workspace (bytes), peak ~96.9 MB (known-good budget)
    char* w = (char*)d_ws;
    unsigned short* z1c  = (unsigned short*)(w);                 // 32,768,000
    unsigned short* h1c  = (unsigned short*)(w + 32768000);      // 32,768,000
    unsigned short* z2c  = (unsigned short*)(w + 65536000);      //  8,192,000
    float*          s1s  = (float*)        (w + 73728000);       //  1,024,000
    float*          s1d  = (float*)        (w + 74752000);       //  1,024,000
    float*          s2s  = (float*)        (w + 75776000);       //    256,000
    float*          s2d  = (float*)        (w + 76032000);       //    256,000
    unsigned short* gib2 = (unsigned short*)(w);                 // 49,152,000 (after chunks)
    unsigned short* h2b  = (unsigned short*)(w + 76288000);      // 16,384,000
    unsigned short* W1T  = (unsigned short*)(w + 92672000);      //     65,536
    unsigned short* W2T  = (unsigned short*)(w + 92737536);      //     32,768
    unsigned short* WihB = (unsigned short*)(w + 92770304);      //     24,576
    unsigned short* WhhB = (unsigned short*)(w + 92794880);      //     24,576
    float*          hloc = (float*)        (w + 92819456);       //  4,096,000 -> 96,915,456

    k_cvt_w<<<288, 256, 0, stream>>>(W1, W2, Wih, Whh, W1T, W2T, WihB, WhhB);

    for (int c = 0; c < 64 / CB_; c++) {
        int bt0 = c * CB_;
        k_mz1<<<1000, 256, 0, stream>>>(dyn, W1T, b1, a1, z1c, s1s, s1d, bt0);
        k_agg<<<16000, 256, 0, stream>>>(z1c, s1s, s1d, a1b, src, h1c, H_, 256, 0);
        k_mz2<<<1000, 256, 0, stream>>>(h1c, W2T, b2, a2, z2c, s2s, s2d);
        k_agg<<<4000, 256, 0, stream>>>(z2c, s2s, s2d, a2b, src, h2b, 1, 64, bt0);
    }
    k_mgi<<<dim3(2000, 3), 256, 0, stream>>>(h2b, WihB, bih, gib2);
    k_gru<<<500, 256, 0, stream>>>(gib2, WhhB, bhh, h0, hloc);
    k_proj<<<1000, 256, 0, stream>>>(hloc, Wp, bp, out);
}

// Round 7
// 528.975 us; speedup vs baseline: 1.1689x; 1.0687x over previous
//
#include <hip/hip_runtime.h>

// Problem constants
#define B_ 8
#define N_ 2000
#define T_ 8
#define F_ 128
#define DEG_ 8
#define H_ 4
#define G_ 64
#define PW_ 16
#define SEQ_ (N_ * T_)   // 16000

typedef short s8v __attribute__((ext_vector_type(8)));            // 8 bf16
typedef unsigned short u8v __attribute__((ext_vector_type(8)));   // 8 bf16 (loads)
typedef float f4v __attribute__((ext_vector_type(4)));            // MFMA acc

static __device__ __forceinline__ unsigned short f2bf(float f) {
    unsigned int u = __float_as_uint(f);
    u += 0x7FFFu + ((u >> 16) & 1u);         // RNE
    return (unsigned short)(u >> 16);
}
static __device__ __forceinline__ float bf2f(unsigned short b) {
    return __uint_as_float(((unsigned int)b) << 16);
}
static __device__ __forceinline__ s8v pack8(float4 u, float4 v) {
    s8v r;
    r[0] = (short)f2bf(u.x); r[1] = (short)f2bf(u.y);
    r[2] = (short)f2bf(u.z); r[3] = (short)f2bf(u.w);
    r[4] = (short)f2bf(v.x); r[5] = (short)f2bf(v.y);
    r[6] = (short)f2bf(v.z); r[7] = (short)f2bf(v.w);
    return r;
}

// ---------------- weight prep: W1T[h][d][f], W2T[d][k], WihB[j][k], WhhB (bf16) ----------------
__global__ void k_cvt_w(const float* __restrict__ W1, const float* __restrict__ W2,
                        const float* __restrict__ Wih, const float* __restrict__ Whh,
                        unsigned short* __restrict__ W1T, unsigned short* __restrict__ W2T,
                        unsigned short* __restrict__ WihB, unsigned short* __restrict__ WhhB)
{
    int idx = blockIdx.x * 256 + threadIdx.x;      // 73,728 total
    if (idx < 32768) {                              // W1 (4,128,64) -> [h][d][f]
        int h = idx >> 13, rem = idx & 8191;
        int d = rem >> 7, f = rem & 127;
        W1T[idx] = f2bf(W1[h * 8192 + f * 64 + d]);
    } else if (idx < 49152) {                       // W2 (256,64) -> [d][k]
        int i = idx - 32768;
        int d = i >> 8, k = i & 255;
        W2T[i] = f2bf(W2[k * 64 + d]);
    } else if (idx < 61440) {                       // Wih (192,64) straight
        int i = idx - 49152;
        WihB[i] = f2bf(Wih[i]);
    } else if (idx < 73728) {                       // Whh (192,64) straight
        int i = idx - 61440;
        WhhB[i] = f2bf(Whh[i]);
    }
}

// ---------------- z1 GEMM (A=W1T, B=activations) + fused scores (bf16 scores) ----------------
__global__ __launch_bounds__(256) void k_mz1(
    const float* __restrict__ dyn, const unsigned short* __restrict__ W1T,
    const float* __restrict__ b1, const float* __restrict__ a1,
    unsigned short* __restrict__ z1c, unsigned short* __restrict__ s1s,
    unsigned short* __restrict__ s1d)
{
    const int tid = threadIdx.x, w = tid >> 6, l = tid & 63;
    const int lr = l & 15, lq = l >> 4;
    const int r0 = blockIdx.x * 64 + w * 16;       // row strip over 64*2000 rows
    const int btl = r0 / 2000, n0 = r0 - btl * 2000;
    const int b = btl >> 3, t = btl & 7;

    const float* Bp = dyn + (((size_t)(b * 2000) + n0 + lr) * 8 + t) * 128 + lq * 8;

    f4v acc[4][4] = {};
    #pragma unroll
    for (int ks = 0; ks < 4; ks++) {
        float4 u = *(const float4*)(Bp + ks * 32);
        float4 v = *(const float4*)(Bp + ks * 32 + 4);
        s8v bfrag = pack8(u, v);
        #pragma unroll
        for (int h = 0; h < 4; h++)
            #pragma unroll
            for (int dm = 0; dm < 4; dm++) {
                s8v a = *(const s8v*)(W1T + ((size_t)(h * 64 + dm * 16 + lr)) * 128 + lq * 8 + ks * 32);
                acc[h][dm] = __builtin_amdgcn_mfma_f32_16x16x32_bf16(a, bfrag, acc[h][dm], 0, 0, 0);
            }
    }

    const int node = n0 + lr;
    #pragma unroll
    for (int h = 0; h < 4; h++) {
        const size_t zrow = (size_t)(btl * 4 + h) * 2000 + node;
        float ps = 0.f, pd = 0.f;
        #pragma unroll
        for (int dm = 0; dm < 4; dm++) {
            const int d0 = dm * 16 + lq * 4;
            float4 bi = *(const float4*)(b1 + h * 64 + d0);
            float4 as = *(const float4*)(a1 + h * 128 + d0);
            float4 ad = *(const float4*)(a1 + h * 128 + 64 + d0);
            ushort4 st; float vv;
            vv = acc[h][dm][0] + bi.x; st.x = f2bf(vv); ps = fmaf(vv, as.x, ps); pd = fmaf(vv, ad.x, pd);
            vv = acc[h][dm][1] + bi.y; st.y = f2bf(vv); ps = fmaf(vv, as.y, ps); pd = fmaf(vv, ad.y, pd);
            vv = acc[h][dm][2] + bi.z; st.z = f2bf(vv); ps = fmaf(vv, as.z, ps); pd = fmaf(vv, ad.z, pd);
            vv = acc[h][dm][3] + bi.w; st.w = f2bf(vv); ps = fmaf(vv, as.w, ps); pd = fmaf(vv, ad.w, pd);
            *(ushort4*)(z1c + zrow * 64 + d0) = st;
        }
        ps += __shfl_xor(ps, 16); ps += __shfl_xor(ps, 32);
        pd += __shfl_xor(pd, 16); pd += __shfl_xor(pd, 32);
        if (lq == 0) { s1s[zrow] = f2bf(ps); s1d[zrow] = f2bf(pd); }
    }
}

// ---------------- z2 GEMM + fused scores. K=256 ----------------
__global__ __launch_bounds__(256) void k_mz2(
    const unsigned short* __restrict__ h1c, const unsigned short* __restrict__ W2T,
    const float* __restrict__ b2, const float* __restrict__ a2,
    unsigned short* __restrict__ z2c, unsigned short* __restrict__ s2s,
    unsigned short* __restrict__ s2d)
{
    const int tid = threadIdx.x, w = tid >> 6, l = tid & 63;
    const int lr = l & 15, lq = l >> 4;
    const int r0 = blockIdx.x * 64 + w * 16;

    const unsigned short* Bp = h1c + (size_t)(r0 + lr) * 256 + lq * 8;

    f4v acc[4] = {};
    #pragma unroll
    for (int ks = 0; ks < 8; ks++) {
        s8v bfrag = *(const s8v*)(Bp + ks * 32);
        #pragma unroll
        for (int dm = 0; dm < 4; dm++) {
            s8v a = *(const s8v*)(W2T + ((size_t)(dm * 16 + lr)) * 256 + lq * 8 + ks * 32);
            acc[dm] = __builtin_amdgcn_mfma_f32_16x16x32_bf16(a, bfrag, acc[dm], 0, 0, 0);
        }
    }

    const int node = r0 + lr;
    float ps = 0.f, pd = 0.f;
    #pragma unroll
    for (int dm = 0; dm < 4; dm++) {
        const int d0 = dm * 16 + lq * 4;
        float4 bi = *(const float4*)(b2 + d0);
        float4 as = *(const float4*)(a2 + d0);
        float4 ad = *(const float4*)(a2 + 64 + d0);
        ushort4 st; float vv;
        vv = acc[dm][0] + bi.x; st.x = f2bf(vv); ps = fmaf(vv, as.x, ps); pd = fmaf(vv, ad.x, pd);
        vv = acc[dm][1] + bi.y; st.y = f2bf(vv); ps = fmaf(vv, as.y, ps); pd = fmaf(vv, ad.y, pd);
        vv = acc[dm][2] + bi.z; st.z = f2bf(vv); ps = fmaf(vv, as.z, ps); pd = fmaf(vv, ad.z, pd);
        vv = acc[dm][3] + bi.w; st.w = f2bf(vv); ps = fmaf(vv, as.w, ps); pd = fmaf(vv, ad.w, pd);
        *(ushort4*)(z2c + (size_t)node * 64 + d0) = st;
    }
    ps += __shfl_xor(ps, 16); ps += __shfl_xor(ps, 32);
    pd += __shfl_xor(pd, 16); pd += __shfl_xor(pd, 32);
    if (lq == 0) { s2s[node] = f2bf(ps); s2d[node] = f2bf(pd); }
}

// ---------------- gi GEMM -> node-blocked gib2[b][n][c][t] ----------------
__global__ __launch_bounds__(256) void k_mgi(
    const unsigned short* __restrict__ h2b, const unsigned short* __restrict__ WihB,
    const float* __restrict__ bih, unsigned short* __restrict__ gib2)
{
    const int tid = threadIdx.x, w = tid >> 6, l = tid & 63;
    const int lr = l & 15, lq = l >> 4;
    const int r0 = blockIdx.x * 64 + w * 16;
    const int col0 = blockIdx.y * 64;

    const int rA = r0 + lr;
    const int bA = rA / 16000;
    const int remA = rA - bA * 16000;
    const int nAr = remA >> 3, tA = remA & 7;
    const unsigned short* Ab = h2b + ((size_t)((bA * 8 + tA) * 2000) + nAr) * 64 + lq * 8;

    f4v acc[4] = {};
    #pragma unroll
    for (int ks = 0; ks < 2; ks++) {
        s8v a = *(const s8v*)(Ab + ks * 32);
        #pragma unroll
        for (int nt = 0; nt < 4; nt++) {
            s8v bfr = *(const s8v*)(WihB + ((size_t)(col0 + nt * 16 + lr)) * 64 + lq * 8 + ks * 32);
            acc[nt] = __builtin_amdgcn_mfma_f32_16x16x32_bf16(a, bfr, acc[nt], 0, 0, 0);
        }
    }
    const int rrb = r0 + lq * 4;
    const int bO = rrb / 16000;
    const int remO = rrb - bO * 16000;
    const int nO = remO >> 3, tO = remO & 7;
    #pragma unroll
    for (int nt = 0; nt < 4; nt++) {
        int cc = col0 + nt * 16 + lr;
        float bias = bih[cc];
        ushort4 st;
        st.x = f2bf(acc[nt][0] + bias); st.y = f2bf(acc[nt][1] + bias);
        st.z = f2bf(acc[nt][2] + bias); st.w = f2bf(acc[nt][3] + bias);
        *(ushort4*)(gib2 + (((size_t)(bO * 2000 + nO)) * 192 + cc) * 8 + tO) = st;
    }
}

// ---------------- edge softmax + aggregation + ELU, 4 rows per wave ----------------
__global__ void k_agg(const unsigned short* __restrict__ z, const unsigned short* __restrict__ ssrc,
                      const unsigned short* __restrict__ sdst, const float* __restrict__ ab,
                      const int* __restrict__ src, unsigned short* __restrict__ out,
                      int Hn, int outStride)
{
    const int wv = threadIdx.x >> 6, lane = threadIdx.x & 63;
    const int rbase = blockIdx.x * 16 + wv * 4;

    int siA[4][8]; float ssA[4][8]; unsigned short zsA[4][8];
    float sdA[4]; int nA[4], bthA[4];
    #pragma unroll
    for (int rw = 0; rw < 4; rw++) {
        int row = rbase + rw;
        int bth = row / N_; int n = row - bth * N_;
        nA[rw] = n; bthA[rw] = bth;
        int4 s0 = *(const int4*)(src + n * 8);
        int4 s1 = *(const int4*)(src + n * 8 + 4);
        siA[rw][0] = s0.x; siA[rw][1] = s0.y; siA[rw][2] = s0.z; siA[rw][3] = s0.w;
        siA[rw][4] = s1.x; siA[rw][5] = s1.y; siA[rw][6] = s1.z; siA[rw][7] = s1.w;
    }
    #pragma unroll
    for (int rw = 0; rw < 4; rw++)
        #pragma unroll
        for (int k = 0; k < 8; k++)
            ssA[rw][k] = bf2f(ssrc[(size_t)bthA[rw] * N_ + siA[rw][k]]);
    #pragma unroll
    for (int rw = 0; rw < 4; rw++)
        #pragma unroll
        for (int k = 0; k < 8; k++)
            zsA[rw][k] = z[((size_t)bthA[rw] * N_ + siA[rw][k]) * 64 + lane];
    #pragma unroll
    for (int rw = 0; rw < 4; rw++)
        sdA[rw] = bf2f(sdst[rbase + rw]) + ab[bthA[rw] % Hn];

    #pragma unroll
    for (int rw = 0; rw < 4; rw++) {
        float e[8];
        #pragma unroll
        for (int k = 0; k < 8; k++) {
            float ev = ssA[rw][k] + sdA[rw];
            e[k] = ev > 0.f ? ev : 0.01f * ev;
        }
        float m = e[0];
        #pragma unroll
        for (int k = 1; k < 8; k++) m = fmaxf(m, e[k]);
        float sum = 0.f;
        #pragma unroll
        for (int k = 0; k < 8; k++) { e[k] = __expf(e[k] - m); sum += e[k]; }
        float inv = 1.f / sum;
        float acc = 0.f;
        #pragma unroll
        for (int k = 0; k < 8; k++) acc = fmaf(e[k], bf2f(zsA[rw][k]), acc);
        acc *= inv;
        acc = acc > 0.f ? acc : (__expf(acc) - 1.f);
        int h = bthA[rw] % Hn, btl = bthA[rw] / Hn;
        out[((size_t)btl * N_ + nA[rw]) * outStride + h * 64 + lane] = f2bf(acc);
    }
}

// ---------------- MFMA GRU: 250 blocks, TWO chain-groups per block ----------------
// Cols 0-7 = batches of chain q, cols 8-15 = batches of chain q+250. Per step one
// Whh(192x64)@H(64x16) MFMA set serves both. Warm 3 nodes + 4 real = 7 nodes x 8 steps.
__global__ __launch_bounds__(256) void k_gru(
    const unsigned short* __restrict__ gib2, const unsigned short* __restrict__ WhhB,
    const float* __restrict__ bhh, const float* __restrict__ h0,
    float* __restrict__ hloc)
{
    const int q = blockIdx.x;                 // [0,250)
    const int tid = threadIdx.x;
    const int w = tid >> 6, l = tid & 63;
    const int lr = l & 15, lq = l >> 4;
    const int j0 = w * 16 + lq * 4;
    const int bb = lr & 7;                    // batch
    const int grp = lr >> 3;                  // chain group 0/1
    const int Q = q + grp * 250;              // chain id [0,500)

    __shared__ unsigned short hbuf[3][16][72];
    {
        unsigned int* p = (unsigned int*)hbuf;
        #pragma unroll 1
        for (int i = tid; i < 3 * 16 * 72 / 2; i += 256) p[i] = 0u;
    }
    __syncthreads();

    const int jrow = w * 16 + lr;
    s8v wR0 = *(const s8v*)(WhhB + (size_t)jrow * 64 + lq * 8);
    s8v wR1 = *(const s8v*)(WhhB + (size_t)jrow * 64 + 32 + lq * 8);
    s8v wZ0 = *(const s8v*)(WhhB + (size_t)(64 + jrow) * 64 + lq * 8);
    s8v wZ1 = *(const s8v*)(WhhB + (size_t)(64 + jrow) * 64 + 32 + lq * 8);
    s8v wN0 = *(const s8v*)(WhhB + (size_t)(128 + jrow) * 64 + lq * 8);
    s8v wN1 = *(const s8v*)(WhhB + (size_t)(128 + jrow) * 64 + 32 + lq * 8);

    float4 t4;
    t4 = *(const float4*)(bhh + j0);        float bhr_[4] = {t4.x, t4.y, t4.z, t4.w};
    t4 = *(const float4*)(bhh + 64 + j0);   float bhz_[4] = {t4.x, t4.y, t4.z, t4.w};
    t4 = *(const float4*)(bhh + 128 + j0);  float bhn_[4] = {t4.x, t4.y, t4.z, t4.w};

    float hp[4] = {0.f, 0.f, 0.f, 0.f};
    if (Q == 0) {                             // chain 0 starts from exact h0
        float4 h04 = *(const float4*)(h0 + bb * 64 + j0);
        hp[0] = h04.x; hp[1] = h04.y; hp[2] = h04.z; hp[3] = h04.w;
        ushort4 st;
        st.x = f2bf(hp[0]); st.y = f2bf(hp[1]); st.z = f2bf(hp[2]); st.w = f2bf(hp[3]);
        *(ushort4*)&hbuf[0][lr][j0] = st;
    }
    __syncthreads();

    const unsigned short* gbase = gib2 + ((size_t)bb * 2000) * 192 * 8;
    const int ndF = Q * 4 - 3;                // first (warm) node; <0 only for Q==0

    int ndc = ndF < 0 ? 0 : ndF;
    u8v cRv[4], cZv[4], cNv[4];
    #pragma unroll
    for (int rg = 0; rg < 4; rg++) {
        cRv[rg] = *(const u8v*)(gbase + (((size_t)ndc * 192 + j0 + rg)) * 8);
        cZv[rg] = *(const u8v*)(gbase + (((size_t)ndc * 192 + 64 + j0 + rg)) * 8);
        cNv[rg] = *(const u8v*)(gbase + (((size_t)ndc * 192 + 128 + j0 + rg)) * 8);
    }

    int sb = 0;
    for (int o = 0; o < 7; ++o) {
        const int nd = ndF + o;               // per-lane (group-dependent)
        u8v nRv[4] = {}, nZv[4] = {}, nNv[4] = {};
        if (o < 6) {
            int ndn = nd + 1; if (ndn < 0) ndn = 0;
            #pragma unroll
            for (int rg = 0; rg < 4; rg++) {
                nRv[rg] = *(const u8v*)(gbase + (((size_t)ndn * 192 + j0 + rg)) * 8);
                nZv[rg] = *(const u8v*)(gbase + (((size_t)ndn * 192 + 64 + j0 + rg)) * 8);
                nNv[rg] = *(const u8v*)(gbase + (((size_t)ndn * 192 + 128 + j0 + rg)) * 8);
            }
        }
        #pragma unroll
        for (int ts = 0; ts < 8; ts++) {
            const unsigned short* hbp = &hbuf[sb][lr][0];
            s8v hb0 = *(const s8v*)(hbp + lq * 8);
            s8v hb1 = *(const s8v*)(hbp + 32 + lq * 8);

            f4v aR = {}, aZ = {}, aN = {};
            aR = __builtin_amdgcn_mfma_f32_16x16x32_bf16(wR0, hb0, aR, 0, 0, 0);
            aR = __builtin_amdgcn_mfma_f32_16x16x32_bf16(wR1, hb1, aR, 0, 0, 0);
            aZ = __builtin_amdgcn_mfma_f32_16x16x32_bf16(wZ0, hb0, aZ, 0, 0, 0);
            aZ = __builtin_amdgcn_mfma_f32_16x16x32_bf16(wZ1, hb1, aZ, 0, 0, 0);
            aN = __builtin_amdgcn_mfma_f32_16x16x32_bf16(wN0, hb0, aN, 0, 0, 0);
            aN = __builtin_amdgcn_mfma_f32_16x16x32_bf16(wN1, hb1, aN, 0, 0, 0);

            #pragma unroll
            for (int rg = 0; rg < 4; rg++) {
                float gr = bf2f((unsigned short)cRv[rg][ts]);
                float gz = bf2f((unsigned short)cZv[rg][ts]);
                float gn = bf2f((unsigned short)cNv[rg][ts]);
                float rr = 1.f / (1.f + __expf(-(gr + aR[rg] + bhr_[rg])));
                float zz = 1.f / (1.f + __expf(-(gz + aZ[rg] + bhz_[rg])));
                float tn = gn + rr * (aN[rg] + bhn_[rg]);
                float nn = 1.f - 2.f / (__expf(2.f * tn) + 1.f);
                float hnew = (1.f - zz) * nn + zz * hp[rg];
                hp[rg] = (nd >= 0) ? hnew : hp[rg];   // mask pre-history (chain 0 only)
            }

            int nsb = sb + 1; if (nsb == 3) nsb = 0;
            ushort4 st;
            st.x = f2bf(hp[0]); st.y = f2bf(hp[1]);
            st.z = f2bf(hp[2]); st.w = f2bf(hp[3]);
            *(ushort4*)&hbuf[nsb][lr][j0] = st;
            if (ts == 7 && o >= 3) {               // real nodes
                float4 ov; ov.x = hp[0]; ov.y = hp[1]; ov.z = hp[2]; ov.w = hp[3];
                *(float4*)(hloc + ((size_t)nd * 8 + bb) * 64 + j0) = ov;
            }
            __syncthreads();
            sb = nsb;
        }
        #pragma unroll
        for (int rg = 0; rg < 4; rg++) {
            cRv[rg] = nRv[rg]; cZv[rg] = nZv[rg]; cNv[rg] = nNv[rg];
        }
    }
}

// ---------------- final projection ----------------
__global__ void k_proj(const float* __restrict__ hloc, const float* __restrict__ Wp,
                       const float* __restrict__ bp, float* __restrict__ out)
{
    int idx = blockIdx.x * 256 + threadIdx.x;   // 256000 total
    int p = idx & 15;
    int b = (idx >> 4) & 7;
    int n = idx >> 7;
    const float* hr = hloc + ((size_t)n * B_ + b) * 64;
    float acc = bp[p];
    #pragma unroll
    for (int jj = 0; jj < 64; jj++) acc = fmaf(hr[jj], Wp[jj * 16 + p], acc);
    out[((size_t)b * N_ + n) * PW_ + p] = acc;
}

extern "C" void kernel_launch(void* const* d_in, const int* in_sizes, int n_in,
                              void* d_out, int out_size, void* d_ws, size_t ws_size,
                              hipStream_t stream) {
    const float* dyn  = (const float*)d_in[0];
    const float* h0   = (const float*)d_in[1];
    const int*   src  = (const int*)  d_in[2];
    const float* W1   = (const float*)d_in[3];
    const float* b1   = (const float*)d_in[4];
    const float* a1   = (const float*)d_in[5];
    const float* a1b  = (const float*)d_in[6];
    const float* W2   = (const float*)d_in[7];
    const float* b2   = (const float*)d_in[8];
    const float* a2   = (const float*)d_in[9];
    const float* a2b  = (const float*)d_in[10];
    const float* Wih  = (const float*)d_in[11];
    const float* Whh  = (const float*)d_in[12];
    const float* bih  = (const float*)d_in[13];
    const float* bhh  = (const float*)d_in[14];
    const float* Wp   = (const float*)d_in[15];
    const float* bp   = (const float*)d_in[16];
    float* out = (float*)d_out;

    // Workspace (bytes), peak 133,267,456 B — under the proven 135,168,000 budget.
    // Phase 1: z1c [0,65.536M) + h1c [65.536,131.072M) + s1s/s1d bf16 + tables.
    // Phase 2 overlays the z1c region (dead after agg1) and h1c region (dead after mz2).
    char* w = (char*)d_ws;
    unsigned short* z1c  = (unsigned short*)(w);                  // 65,536,000
    unsigned short* h1c  = (unsigned short*)(w + 65536000);       // 65,536,000
    unsigned short* s1s  = (unsigned short*)(w + 131072000);      //  1,024,000 (bf16)
    unsigned short* s1d  = (unsigned short*)(w + 132096000);      //  1,024,000
    unsigned short* W1T  = (unsigned short*)(w + 133120000);      //     65,536
    unsigned short* W2T  = (unsigned short*)(w + 133185536);      //     32,768
    unsigned short* WihB = (unsigned short*)(w + 133218304);      //     24,576
    unsigned short* WhhB = (unsigned short*)(w + 133242880);      //     24,576 -> 133,267,456
    unsigned short* z2c  = (unsigned short*)(w);                  // 16,384,000 (over dead z1c)
    unsigned short* s2s  = (unsigned short*)(w + 16384000);       //    256,000
    unsigned short* s2d  = (unsigned short*)(w + 16640000);       //    256,000
    unsigned short* h2b  = (unsigned short*)(w + 16896000);       // 16,384,000 -> 33,280,000
    float*          hloc = (float*)        (w + 33280000);        //  4,096,000 -> 37,376,000
    unsigned short* gib2 = (unsigned short*)(w + 65536000);       // 49,152,000 (over dead h1c)

    k_cvt_w<<<288, 256, 0, stream>>>(W1, W2, Wih, Whh, W1T, W2T, WihB, WhhB);

    // Single-chunk GAT pipeline (all 64 (b,t) slices at once)
    k_mz1<<<2000, 256, 0, stream>>>(dyn, W1T, b1, a1, z1c, s1s, s1d);
    k_agg<<<32000, 256, 0, stream>>>(z1c, s1s, s1d, a1b, src, h1c, H_, 256);
    k_mz2<<<2000, 256, 0, stream>>>(h1c, W2T, b2, a2, z2c, s2s, s2d);
    k_agg<<<8000, 256, 0, stream>>>(z2c, s2s, s2d, a2b, src, h2b, 1, 64);

    k_mgi<<<dim3(2000, 3), 256, 0, stream>>>(h2b, WihB, bih, gib2);
    k_gru<<<250, 256, 0, stream>>>(gib2, WhhB, bhh, h0, hloc);
    k_proj<<<1000, 256, 0, stream>>>(hloc, Wp, bp, out);
}

// Round 8
// 464.245 us; speedup vs baseline: 1.3319x; 1.1394x over previous
//
#include <hip/hip_runtime.h>

// Problem constants
#define B_ 8
#define N_ 2000
#define T_ 8
#define F_ 128
#define DEG_ 8
#define H_ 4
#define G_ 64
#define PW_ 16
#define SEQ_ (N_ * T_)   // 16000
#define CB_ 32           // (b,t) slices per chunk; 2 chunks

typedef short s8v __attribute__((ext_vector_type(8)));            // 8 bf16
typedef unsigned short u8v __attribute__((ext_vector_type(8)));   // 8 bf16 (loads)
typedef float f4v __attribute__((ext_vector_type(4)));            // MFMA acc

static __device__ __forceinline__ unsigned short f2bf(float f) {
    unsigned int u = __float_as_uint(f);
    u += 0x7FFFu + ((u >> 16) & 1u);         // RNE
    return (unsigned short)(u >> 16);
}
static __device__ __forceinline__ float bf2f(unsigned short b) {
    return __uint_as_float(((unsigned int)b) << 16);
}
static __device__ __forceinline__ s8v pack8(float4 u, float4 v) {
    s8v r;
    r[0] = (short)f2bf(u.x); r[1] = (short)f2bf(u.y);
    r[2] = (short)f2bf(u.z); r[3] = (short)f2bf(u.w);
    r[4] = (short)f2bf(v.x); r[5] = (short)f2bf(v.y);
    r[6] = (short)f2bf(v.z); r[7] = (short)f2bf(v.w);
    return r;
}

// ---------------- weight prep: W1T[h][d][f], W2T[d][k], WihB[j][k], WhhB (bf16) ----------------
__global__ void k_cvt_w(const float* __restrict__ W1, const float* __restrict__ W2,
                        const float* __restrict__ Wih, const float* __restrict__ Whh,
                        unsigned short* __restrict__ W1T, unsigned short* __restrict__ W2T,
                        unsigned short* __restrict__ WihB, unsigned short* __restrict__ WhhB)
{
    int idx = blockIdx.x * 256 + threadIdx.x;      // 73,728 total
    if (idx < 32768) {                              // W1 (4,128,64) -> [h][d][f]
        int h = idx >> 13, rem = idx & 8191;
        int d = rem >> 7, f = rem & 127;
        W1T[idx] = f2bf(W1[h * 8192 + f * 64 + d]);
    } else if (idx < 49152) {                       // W2 (256,64) -> [d][k]
        int i = idx - 32768;
        int d = i >> 8, k = i & 255;
        W2T[i] = f2bf(W2[k * 64 + d]);
    } else if (idx < 61440) {                       // Wih (192,64) straight
        int i = idx - 49152;
        WihB[i] = f2bf(Wih[i]);
    } else if (idx < 73728) {                       // Whh (192,64) straight
        int i = idx - 61440;
        WhhB[i] = f2bf(Whh[i]);
    }
}

// ---------------- z1 GEMM (A=W1T, B=activations) + fused scores (bf16) ----------------
__global__ __launch_bounds__(256) void k_mz1(
    const float* __restrict__ dyn, const unsigned short* __restrict__ W1T,
    const float* __restrict__ b1, const float* __restrict__ a1,
    unsigned short* __restrict__ z1c, unsigned short* __restrict__ s1s,
    unsigned short* __restrict__ s1d, int bt0)
{
    const int tid = threadIdx.x, w = tid >> 6, l = tid & 63;
    const int lr = l & 15, lq = l >> 4;
    const int r0 = blockIdx.x * 64 + w * 16;       // local row strip over CB_*2000
    const int btl = r0 / 2000, n0 = r0 - btl * 2000;
    const int bt = bt0 + btl, b = bt >> 3, t = bt & 7;

    const float* Bp = dyn + (((size_t)(b * 2000) + n0 + lr) * 8 + t) * 128 + lq * 8;

    f4v acc[4][4] = {};
    #pragma unroll
    for (int ks = 0; ks < 4; ks++) {
        float4 u = *(const float4*)(Bp + ks * 32);
        float4 v = *(const float4*)(Bp + ks * 32 + 4);
        s8v bfrag = pack8(u, v);
        #pragma unroll
        for (int h = 0; h < 4; h++)
            #pragma unroll
            for (int dm = 0; dm < 4; dm++) {
                s8v a = *(const s8v*)(W1T + ((size_t)(h * 64 + dm * 16 + lr)) * 128 + lq * 8 + ks * 32);
                acc[h][dm] = __builtin_amdgcn_mfma_f32_16x16x32_bf16(a, bfrag, acc[h][dm], 0, 0, 0);
            }
    }

    const int node = n0 + lr;
    #pragma unroll
    for (int h = 0; h < 4; h++) {
        const size_t zrow = (size_t)(btl * 4 + h) * 2000 + node;
        float ps = 0.f, pd = 0.f;
        #pragma unroll
        for (int dm = 0; dm < 4; dm++) {
            const int d0 = dm * 16 + lq * 4;
            float4 bi = *(const float4*)(b1 + h * 64 + d0);
            float4 as = *(const float4*)(a1 + h * 128 + d0);
            float4 ad = *(const float4*)(a1 + h * 128 + 64 + d0);
            ushort4 st; float vv;
            vv = acc[h][dm][0] + bi.x; st.x = f2bf(vv); ps = fmaf(vv, as.x, ps); pd = fmaf(vv, ad.x, pd);
            vv = acc[h][dm][1] + bi.y; st.y = f2bf(vv); ps = fmaf(vv, as.y, ps); pd = fmaf(vv, ad.y, pd);
            vv = acc[h][dm][2] + bi.z; st.z = f2bf(vv); ps = fmaf(vv, as.z, ps); pd = fmaf(vv, ad.z, pd);
            vv = acc[h][dm][3] + bi.w; st.w = f2bf(vv); ps = fmaf(vv, as.w, ps); pd = fmaf(vv, ad.w, pd);
            *(ushort4*)(z1c + zrow * 64 + d0) = st;
        }
        ps += __shfl_xor(ps, 16); ps += __shfl_xor(ps, 32);
        pd += __shfl_xor(pd, 16); pd += __shfl_xor(pd, 32);
        if (lq == 0) { s1s[zrow] = f2bf(ps); s1d[zrow] = f2bf(pd); }
    }
}

// ---------------- z2 GEMM + fused scores. K=256 ----------------
__global__ __launch_bounds__(256) void k_mz2(
    const unsigned short* __restrict__ h1c, const unsigned short* __restrict__ W2T,
    const float* __restrict__ b2, const float* __restrict__ a2,
    unsigned short* __restrict__ z2c, unsigned short* __restrict__ s2s,
    unsigned short* __restrict__ s2d)
{
    const int tid = threadIdx.x, w = tid >> 6, l = tid & 63;
    const int lr = l & 15, lq = l >> 4;
    const int r0 = blockIdx.x * 64 + w * 16;

    const unsigned short* Bp = h1c + (size_t)(r0 + lr) * 256 + lq * 8;

    f4v acc[4] = {};
    #pragma unroll
    for (int ks = 0; ks < 8; ks++) {
        s8v bfrag = *(const s8v*)(Bp + ks * 32);
        #pragma unroll
        for (int dm = 0; dm < 4; dm++) {
            s8v a = *(const s8v*)(W2T + ((size_t)(dm * 16 + lr)) * 256 + lq * 8 + ks * 32);
            acc[dm] = __builtin_amdgcn_mfma_f32_16x16x32_bf16(a, bfrag, acc[dm], 0, 0, 0);
        }
    }

    const int node = r0 + lr;
    float ps = 0.f, pd = 0.f;
    #pragma unroll
    for (int dm = 0; dm < 4; dm++) {
        const int d0 = dm * 16 + lq * 4;
        float4 bi = *(const float4*)(b2 + d0);
        float4 as = *(const float4*)(a2 + d0);
        float4 ad = *(const float4*)(a2 + 64 + d0);
        ushort4 st; float vv;
        vv = acc[dm][0] + bi.x; st.x = f2bf(vv); ps = fmaf(vv, as.x, ps); pd = fmaf(vv, ad.x, pd);
        vv = acc[dm][1] + bi.y; st.y = f2bf(vv); ps = fmaf(vv, as.y, ps); pd = fmaf(vv, ad.y, pd);
        vv = acc[dm][2] + bi.z; st.z = f2bf(vv); ps = fmaf(vv, as.z, ps); pd = fmaf(vv, ad.z, pd);
        vv = acc[dm][3] + bi.w; st.w = f2bf(vv); ps = fmaf(vv, as.w, ps); pd = fmaf(vv, ad.w, pd);
        *(ushort4*)(z2c + (size_t)node * 64 + d0) = st;
    }
    ps += __shfl_xor(ps, 16); ps += __shfl_xor(ps, 32);
    pd += __shfl_xor(pd, 16); pd += __shfl_xor(pd, 32);
    if (lq == 0) { s2s[node] = f2bf(ps); s2d[node] = f2bf(pd); }
}

// ---------------- gi GEMM -> node-blocked gib2[b][n][c][t] ----------------
__global__ __launch_bounds__(256) void k_mgi(
    const unsigned short* __restrict__ h2b, const unsigned short* __restrict__ WihB,
    const float* __restrict__ bih, unsigned short* __restrict__ gib2)
{
    const int tid = threadIdx.x, w = tid >> 6, l = tid & 63;
    const int lr = l & 15, lq = l >> 4;
    const int r0 = blockIdx.x * 64 + w * 16;
    const int col0 = blockIdx.y * 64;

    const int rA = r0 + lr;
    const int bA = rA / 16000;
    const int remA = rA - bA * 16000;
    const int nAr = remA >> 3, tA = remA & 7;
    const unsigned short* Ab = h2b + ((size_t)((bA * 8 + tA) * 2000) + nAr) * 64 + lq * 8;

    f4v acc[4] = {};
    #pragma unroll
    for (int ks = 0; ks < 2; ks++) {
        s8v a = *(const s8v*)(Ab + ks * 32);
        #pragma unroll
        for (int nt = 0; nt < 4; nt++) {
            s8v bfr = *(const s8v*)(WihB + ((size_t)(col0 + nt * 16 + lr)) * 64 + lq * 8 + ks * 32);
            acc[nt] = __builtin_amdgcn_mfma_f32_16x16x32_bf16(a, bfr, acc[nt], 0, 0, 0);
        }
    }
    const int rrb = r0 + lq * 4;
    const int bO = rrb / 16000;
    const int remO = rrb - bO * 16000;
    const int nO = remO >> 3, tO = remO & 7;
    #pragma unroll
    for (int nt = 0; nt < 4; nt++) {
        int cc = col0 + nt * 16 + lr;
        float bias = bih[cc];
        ushort4 st;
        st.x = f2bf(acc[nt][0] + bias); st.y = f2bf(acc[nt][1] + bias);
        st.z = f2bf(acc[nt][2] + bias); st.w = f2bf(acc[nt][3] + bias);
        *(ushort4*)(gib2 + (((size_t)(bO * 2000 + nO)) * 192 + cc) * 8 + tO) = st;
    }
}

// ---------------- edge softmax: ONE THREAD PER ROW -> alpha (8 x bf16) ----------------
__global__ void k_alpha(const unsigned short* __restrict__ ssrc,
                        const unsigned short* __restrict__ sdst,
                        const float* __restrict__ ab, const int* __restrict__ src,
                        unsigned short* __restrict__ alf, int Hn)
{
    const int r = blockIdx.x * 256 + threadIdx.x;   // local row
    const int bth = r / 2000, n = r - bth * 2000;
    const int h = bth % Hn;
    const float sd = bf2f(sdst[r]) + ab[h];
    const unsigned short* sp = ssrc + (size_t)bth * 2000;
    int4 s0 = *(const int4*)(src + n * 8);
    int4 s1 = *(const int4*)(src + n * 8 + 4);
    int si[8] = {s0.x, s0.y, s0.z, s0.w, s1.x, s1.y, s1.z, s1.w};
    float e[8];
    #pragma unroll
    for (int k = 0; k < 8; k++) {
        float ev = bf2f(sp[si[k]]) + sd;
        e[k] = ev > 0.f ? ev : 0.01f * ev;          // leaky_relu
    }
    float m = e[0];
    #pragma unroll
    for (int k = 1; k < 8; k++) m = fmaxf(m, e[k]);
    float sum = 0.f;
    #pragma unroll
    for (int k = 0; k < 8; k++) { e[k] = __expf(e[k] - m); sum += e[k]; }
    float inv = 1.f / sum;
    u8v o;
    #pragma unroll
    for (int k = 0; k < 8; k++) o[k] = f2bf(e[k] * inv);
    *(u8v*)(alf + (size_t)r * 8) = o;
}

// ---------------- slim aggregation: gather + weighted sum + ELU, 8 rows/wave ----------------
__global__ void k_agg(const unsigned short* __restrict__ z, const unsigned short* __restrict__ alf,
                      const int* __restrict__ src, unsigned short* __restrict__ out,
                      int Hn, int outStride, int bt0base)
{
    const int wv = threadIdx.x >> 6, lane = threadIdx.x & 63;
    const int rbase = blockIdx.x * 32 + wv * 8;     // 8 rows, all same bth (2000%8==0)
    const int bth = rbase / 2000;
    const int n0 = rbase - bth * 2000;
    const size_t zb = (size_t)bth * 2000;

    unsigned short zs[8][8];
    u8v av[8];
    #pragma unroll
    for (int rw = 0; rw < 8; rw++) {
        int4 s0 = *(const int4*)(src + (n0 + rw) * 8);
        int4 s1 = *(const int4*)(src + (n0 + rw) * 8 + 4);
        int si[8] = {s0.x, s0.y, s0.z, s0.w, s1.x, s1.y, s1.z, s1.w};
        #pragma unroll
        for (int k = 0; k < 8; k++)
            zs[rw][k] = z[(zb + si[k]) * 64 + lane];
        av[rw] = *(const u8v*)(alf + (size_t)(rbase + rw) * 8);
    }
    const int h = bth % Hn, btl = bth / Hn;
    #pragma unroll
    for (int rw = 0; rw < 8; rw++) {
        float acc = 0.f;
        #pragma unroll
        for (int k = 0; k < 8; k++)
            acc = fmaf(bf2f((unsigned short)av[rw][k]), bf2f(zs[rw][k]), acc);
        acc = acc > 0.f ? acc : (__expf(acc) - 1.f);   // ELU
        out[((size_t)(bt0base + btl) * N_ + n0 + rw) * outStride + h * 64 + lane] = f2bf(acc);
    }
}

// ---------------- MFMA GRU: 250 blocks, TWO chain-groups per block ----------------
__global__ __launch_bounds__(256) void k_gru(
    const unsigned short* __restrict__ gib2, const unsigned short* __restrict__ WhhB,
    const float* __restrict__ bhh, const float* __restrict__ h0,
    float* __restrict__ hloc)
{
    const int q = blockIdx.x;                 // [0,250)
    const int tid = threadIdx.x;
    const int w = tid >> 6, l = tid & 63;
    const int lr = l & 15, lq = l >> 4;
    const int j0 = w * 16 + lq * 4;
    const int bb = lr & 7;                    // batch
    const int grp = lr >> 3;                  // chain group 0/1
    const int Q = q + grp * 250;              // chain id [0,500)

    __shared__ unsigned short hbuf[3][16][72];
    {
        unsigned int* p = (unsigned int*)hbuf;
        #pragma unroll 1
        for (int i = tid; i < 3 * 16 * 72 / 2; i += 256) p[i] = 0u;
    }
    __syncthreads();

    const int jrow = w * 16 + lr;
    s8v wR0 = *(const s8v*)(WhhB + (size_t)jrow * 64 + lq * 8);
    s8v wR1 = *(const s8v*)(WhhB + (size_t)jrow * 64 + 32 + lq * 8);
    s8v wZ0 = *(const s8v*)(WhhB + (size_t)(64 + jrow) * 64 + lq * 8);
    s8v wZ1 = *(const s8v*)(WhhB + (size_t)(64 + jrow) * 64 + 32 + lq * 8);
    s8v wN0 = *(const s8v*)(WhhB + (size_t)(128 + jrow) * 64 + lq * 8);
    s8v wN1 = *(const s8v*)(WhhB + (size_t)(128 + jrow) * 64 + 32 + lq * 8);

    float4 t4;
    t4 = *(const float4*)(bhh + j0);        float bhr_[4] = {t4.x, t4.y, t4.z, t4.w};
    t4 = *(const float4*)(bhh + 64 + j0);   float bhz_[4] = {t4.x, t4.y, t4.z, t4.w};
    t4 = *(const float4*)(bhh + 128 + j0);  float bhn_[4] = {t4.x, t4.y, t4.z, t4.w};

    float hp[4] = {0.f, 0.f, 0.f, 0.f};
    if (Q == 0) {
        float4 h04 = *(const float4*)(h0 + bb * 64 + j0);
        hp[0] = h04.x; hp[1] = h04.y; hp[2] = h04.z; hp[3] = h04.w;
        ushort4 st;
        st.x = f2bf(hp[0]); st.y = f2bf(hp[1]); st.z = f2bf(hp[2]); st.w = f2bf(hp[3]);
        *(ushort4*)&hbuf[0][lr][j0] = st;
    }
    __syncthreads();

    const unsigned short* gbase = gib2 + ((size_t)bb * 2000) * 192 * 8;
    const int ndF = Q * 4 - 3;

    int ndc = ndF < 0 ? 0 : ndF;
    u8v cRv[4], cZv[4], cNv[4];
    #pragma unroll
    for (int rg = 0; rg < 4; rg++) {
        cRv[rg] = *(const u8v*)(gbase + (((size_t)ndc * 192 + j0 + rg)) * 8);
        cZv[rg] = *(const u8v*)(gbase + (((size_t)ndc * 192 + 64 + j0 + rg)) * 8);
        cNv[rg] = *(const u8v*)(gbase + (((size_t)ndc * 192 + 128 + j0 + rg)) * 8);
    }

    int sb = 0;
    for (int o = 0; o < 7; ++o) {
        const int nd = ndF + o;
        u8v nRv[4] = {}, nZv[4] = {}, nNv[4] = {};
        if (o < 6) {
            int ndn = nd + 1; if (ndn < 0) ndn = 0;
            #pragma unroll
            for (int rg = 0; rg < 4; rg++) {
                nRv[rg] = *(const u8v*)(gbase + (((size_t)ndn * 192 + j0 + rg)) * 8);
                nZv[rg] = *(const u8v*)(gbase + (((size_t)ndn * 192 + 64 + j0 + rg)) * 8);
                nNv[rg] = *(const u8v*)(gbase + (((size_t)ndn * 192 + 128 + j0 + rg)) * 8);
            }
        }
        #pragma unroll
        for (int ts = 0; ts < 8; ts++) {
            const unsigned short* hbp = &hbuf[sb][lr][0];
            s8v hb0 = *(const s8v*)(hbp + lq * 8);
            s8v hb1 = *(const s8v*)(hbp + 32 + lq * 8);

            f4v aR = {}, aZ = {}, aN = {};
            aR = __builtin_amdgcn_mfma_f32_16x16x32_bf16(wR0, hb0, aR, 0, 0, 0);
            aR = __builtin_amdgcn_mfma_f32_16x16x32_bf16(wR1, hb1, aR, 0, 0, 0);
            aZ = __builtin_amdgcn_mfma_f32_16x16x32_bf16(wZ0, hb0, aZ, 0, 0, 0);
            aZ = __builtin_amdgcn_mfma_f32_16x16x32_bf16(wZ1, hb1, aZ, 0, 0, 0);
            aN = __builtin_amdgcn_mfma_f32_16x16x32_bf16(wN0, hb0, aN, 0, 0, 0);
            aN = __builtin_amdgcn_mfma_f32_16x16x32_bf16(wN1, hb1, aN, 0, 0, 0);

            #pragma unroll
            for (int rg = 0; rg < 4; rg++) {
                float gr = bf2f((unsigned short)cRv[rg][ts]);
                float gz = bf2f((unsigned short)cZv[rg][ts]);
                float gn = bf2f((unsigned short)cNv[rg][ts]);
                float rr = 1.f / (1.f + __expf(-(gr + aR[rg] + bhr_[rg])));
                float zz = 1.f / (1.f + __expf(-(gz + aZ[rg] + bhz_[rg])));
                float tn = gn + rr * (aN[rg] + bhn_[rg]);
                float nn = 1.f - 2.f / (__expf(2.f * tn) + 1.f);
                float hnew = (1.f - zz) * nn + zz * hp[rg];
                hp[rg] = (nd >= 0) ? hnew : hp[rg];
            }

            int nsb = sb + 1; if (nsb == 3) nsb = 0;
            ushort4 st;
            st.x = f2bf(hp[0]); st.y = f2bf(hp[1]);
            st.z = f2bf(hp[2]); st.w = f2bf(hp[3]);
            *(ushort4*)&hbuf[nsb][lr][j0] = st;
            if (ts == 7 && o >= 3) {
                float4 ov; ov.x = hp[0]; ov.y = hp[1]; ov.z = hp[2]; ov.w = hp[3];
                *(float4*)(hloc + ((size_t)nd * 8 + bb) * 64 + j0) = ov;
            }
            __syncthreads();
            sb = nsb;
        }
        #pragma unroll
        for (int rg = 0; rg < 4; rg++) {
            cRv[rg] = nRv[rg]; cZv[rg] = nZv[rg]; cNv[rg] = nNv[rg];
        }
    }
}

// ---------------- final projection ----------------
__global__ void k_proj(const float* __restrict__ hloc, const float* __restrict__ Wp,
                       const float* __restrict__ bp, float* __restrict__ out)
{
    int idx = blockIdx.x * 256 + threadIdx.x;   // 256000 total
    int p = idx & 15;
    int b = (idx >> 4) & 7;
    int n = idx >> 7;
    const float* hr = hloc + ((size_t)n * B_ + b) * 64;
    float acc = bp[p];
    #pragma unroll
    for (int jj = 0; jj < 64; jj++) acc = fmaf(hr[jj], Wp[jj * 16 + p], acc);
    out[((size_t)b * N_ + n) * PW_ + p] = acc;
}

extern "C" void kernel_launch(void* const* d_in, const int* in_sizes, int n_in,
                              void* d_out, int out_size, void* d_ws, size_t ws_size,
                              hipStream_t stream) {
    const float* dyn  = (const float*)d_in[0];
    const float* h0   = (const float*)d_in[1];
    const int*   src  = (const int*)  d_in[2];
    const float* W1   = (const float*)d_in[3];
    const float* b1   = (const float*)d_in[4];
    const float* a1   = (const float*)d_in[5];
    const float* a1b  = (const float*)d_in[6];
    const float* W2   = (const float*)d_in[7];
    const float* b2   = (const float*)d_in[8];
    const float* a2   = (const float*)d_in[9];
    const float* a2b  = (const float*)d_in[10];
    const float* Wih  = (const float*)d_in[11];
    const float* Whh  = (const float*)d_in[12];
    const float* bih  = (const float*)d_in[13];
    const float* bhh  = (const float*)d_in[14];
    const float* Wp   = (const float*)d_in[15];
    const float* bp   = (const float*)d_in[16];
    float* out = (float*)d_out;

    // Workspace (bytes), peak 100,755,456 B — well under proven 121.6 MB budget.
    char* w = (char*)d_ws;
    unsigned short* z1c  = (unsigned short*)(w);                  // 32,768,000 (256k rows x 64)
    unsigned short* h1c  = (unsigned short*)(w + 32768000);       // 32,768,000 (64k x 256)
    unsigned short* z2c  = (unsigned short*)(w + 65536000);       //  8,192,000 (64k x 64)
    unsigned short* s1s  = (unsigned short*)(w + 73728000);       //    512,000
    unsigned short* s1d  = (unsigned short*)(w + 74240000);       //    512,000
    unsigned short* alf1 = (unsigned short*)(w + 74752000);       //  4,096,000 (256k x 8 bf16)
    unsigned short* s2s  = (unsigned short*)(w + 78848000);       //    128,000
    unsigned short* s2d  = (unsigned short*)(w + 78976000);       //    128,000
    unsigned short* alf2 = (unsigned short*)(w + 79104000);       //  1,024,000 (64k x 8 bf16)
    unsigned short* h2b  = (unsigned short*)(w + 80128000);       // 16,384,000 (persistent)
    unsigned short* W1T  = (unsigned short*)(w + 96512000);       //     65,536
    unsigned short* W2T  = (unsigned short*)(w + 96577536);       //     32,768
    unsigned short* WihB = (unsigned short*)(w + 96610304);       //     24,576
    unsigned short* WhhB = (unsigned short*)(w + 96634880);       //     24,576
    float*          hloc = (float*)        (w + 96659456);        //  4,096,000 -> 100,755,456
    unsigned short* gib2 = (unsigned short*)(w);                  // 49,152,000 (over dead chunk scratch)

    k_cvt_w<<<288, 256, 0, stream>>>(W1, W2, Wih, Whh, W1T, W2T, WihB, WhhB);

    for (int c = 0; c < 2; c++) {
        int bt0 = c * CB_;
        k_mz1<<<1000, 256, 0, stream>>>(dyn, W1T, b1, a1, z1c, s1s, s1d, bt0);
        k_alpha<<<1000, 256, 0, stream>>>(s1s, s1d, a1b, src, alf1, H_);
        k_agg<<<8000, 256, 0, stream>>>(z1c, alf1, src, h1c, H_, 256, 0);
        k_mz2<<<1000, 256, 0, stream>>>(h1c, W2T, b2, a2, z2c, s2s, s2d);
        k_alpha<<<250, 256, 0, stream>>>(s2s, s2d, a2b, src, alf2, 1);
        k_agg<<<2000, 256, 0, stream>>>(z2c, alf2, src, h2b, 1, 64, bt0);
    }
    k_mgi<<<dim3(2000, 3), 256, 0, stream>>>(h2b, WihB, bih, gib2);
    k_gru<<<250, 256, 0, stream>>>(gib2, WhhB, bhh, h0, hloc);
    k_proj<<<1000, 256, 0, stream>>>(hloc, Wp, bp, out);
}

// Round 9
// 449.423 us; speedup vs baseline: 1.3758x; 1.0330x over previous
//
#include <hip/hip_runtime.h>

// Problem constants
#define B_ 8
#define N_ 2000
#define T_ 8
#define F_ 128
#define DEG_ 8
#define H_ 4
#define G_ 64
#define PW_ 16
#define SEQ_ (N_ * T_)   // 16000

typedef short s8v __attribute__((ext_vector_type(8)));            // 8 bf16
typedef unsigned short u8v __attribute__((ext_vector_type(8)));   // 8 bf16 (loads)
typedef float f4v __attribute__((ext_vector_type(4)));            // MFMA acc

static __device__ __forceinline__ unsigned short f2bf(float f) {
    unsigned int u = __float_as_uint(f);
    u += 0x7FFFu + ((u >> 16) & 1u);         // RNE
    return (unsigned short)(u >> 16);
}
static __device__ __forceinline__ float bf2f(unsigned short b) {
    return __uint_as_float(((unsigned int)b) << 16);
}
static __device__ __forceinline__ s8v pack8(float4 u, float4 v) {
    s8v r;
    r[0] = (short)f2bf(u.x); r[1] = (short)f2bf(u.y);
    r[2] = (short)f2bf(u.z); r[3] = (short)f2bf(u.w);
    r[4] = (short)f2bf(v.x); r[5] = (short)f2bf(v.y);
    r[6] = (short)f2bf(v.z); r[7] = (short)f2bf(v.w);
    return r;
}

// ---------------- weight prep: W1T[h][d][f], W2T[d][k], WihB[j][k], WhhB (bf16) ----------------
__global__ void k_cvt_w(const float* __restrict__ W1, const float* __restrict__ W2,
                        const float* __restrict__ Wih, const float* __restrict__ Whh,
                        unsigned short* __restrict__ W1T, unsigned short* __restrict__ W2T,
                        unsigned short* __restrict__ WihB, unsigned short* __restrict__ WhhB)
{
    int idx = blockIdx.x * 256 + threadIdx.x;      // 73,728 total
    if (idx < 32768) {                              // W1 (4,128,64) -> [h][d][f]
        int h = idx >> 13, rem = idx & 8191;
        int d = rem >> 7, f = rem & 127;
        W1T[idx] = f2bf(W1[h * 8192 + f * 64 + d]);
    } else if (idx < 49152) {                       // W2 (256,64) -> [d][k]
        int i = idx - 32768;
        int d = i >> 8, k = i & 255;
        W2T[i] = f2bf(W2[k * 64 + d]);
    } else if (idx < 61440) {                       // Wih (192,64) straight
        int i = idx - 49152;
        WihB[i] = f2bf(Wih[i]);
    } else if (idx < 73728) {                       // Whh (192,64) straight
        int i = idx - 61440;
        WhhB[i] = f2bf(Whh[i]);
    }
}

// ---------------- z1 GEMM (A=W1T, B=activations) + fused scores (bf16, single chunk) ----------------
__global__ __launch_bounds__(256) void k_mz1(
    const float* __restrict__ dyn, const unsigned short* __restrict__ W1T,
    const float* __restrict__ b1, const float* __restrict__ a1,
    unsigned short* __restrict__ z1c, unsigned short* __restrict__ s1s,
    unsigned short* __restrict__ s1d)
{
    const int tid = threadIdx.x, w = tid >> 6, l = tid & 63;
    const int lr = l & 15, lq = l >> 4;
    const int r0 = blockIdx.x * 64 + w * 16;       // row strip over 64*2000 rows
    const int btl = r0 / 2000, n0 = r0 - btl * 2000;
    const int b = btl >> 3, t = btl & 7;

    const float* Bp = dyn + (((size_t)(b * 2000) + n0 + lr) * 8 + t) * 128 + lq * 8;

    f4v acc[4][4] = {};
    #pragma unroll
    for (int ks = 0; ks < 4; ks++) {
        float4 u = *(const float4*)(Bp + ks * 32);
        float4 v = *(const float4*)(Bp + ks * 32 + 4);
        s8v bfrag = pack8(u, v);
        #pragma unroll
        for (int h = 0; h < 4; h++)
            #pragma unroll
            for (int dm = 0; dm < 4; dm++) {
                s8v a = *(const s8v*)(W1T + ((size_t)(h * 64 + dm * 16 + lr)) * 128 + lq * 8 + ks * 32);
                acc[h][dm] = __builtin_amdgcn_mfma_f32_16x16x32_bf16(a, bfrag, acc[h][dm], 0, 0, 0);
            }
    }

    const int node = n0 + lr;
    #pragma unroll
    for (int h = 0; h < 4; h++) {
        const size_t zrow = (size_t)(btl * 4 + h) * 2000 + node;
        float ps = 0.f, pd = 0.f;
        #pragma unroll
        for (int dm = 0; dm < 4; dm++) {
            const int d0 = dm * 16 + lq * 4;
            float4 bi = *(const float4*)(b1 + h * 64 + d0);
            float4 as = *(const float4*)(a1 + h * 128 + d0);
            float4 ad = *(const float4*)(a1 + h * 128 + 64 + d0);
            ushort4 st; float vv;
            vv = acc[h][dm][0] + bi.x; st.x = f2bf(vv); ps = fmaf(vv, as.x, ps); pd = fmaf(vv, ad.x, pd);
            vv = acc[h][dm][1] + bi.y; st.y = f2bf(vv); ps = fmaf(vv, as.y, ps); pd = fmaf(vv, ad.y, pd);
            vv = acc[h][dm][2] + bi.z; st.z = f2bf(vv); ps = fmaf(vv, as.z, ps); pd = fmaf(vv, ad.z, pd);
            vv = acc[h][dm][3] + bi.w; st.w = f2bf(vv); ps = fmaf(vv, as.w, ps); pd = fmaf(vv, ad.w, pd);
            *(ushort4*)(z1c + zrow * 64 + d0) = st;
        }
        ps += __shfl_xor(ps, 16); ps += __shfl_xor(ps, 32);
        pd += __shfl_xor(pd, 16); pd += __shfl_xor(pd, 32);
        if (lq == 0) { s1s[zrow] = f2bf(ps); s1d[zrow] = f2bf(pd); }
    }
}

// ---------------- z2 GEMM + fused scores. K=256 ----------------
__global__ __launch_bounds__(256) void k_mz2(
    const unsigned short* __restrict__ h1c, const unsigned short* __restrict__ W2T,
    const float* __restrict__ b2, const float* __restrict__ a2,
    unsigned short* __restrict__ z2c, unsigned short* __restrict__ s2s,
    unsigned short* __restrict__ s2d)
{
    const int tid = threadIdx.x, w = tid >> 6, l = tid & 63;
    const int lr = l & 15, lq = l >> 4;
    const int r0 = blockIdx.x * 64 + w * 16;

    const unsigned short* Bp = h1c + (size_t)(r0 + lr) * 256 + lq * 8;

    f4v acc[4] = {};
    #pragma unroll
    for (int ks = 0; ks < 8; ks++) {
        s8v bfrag = *(const s8v*)(Bp + ks * 32);
        #pragma unroll
        for (int dm = 0; dm < 4; dm++) {
            s8v a = *(const s8v*)(W2T + ((size_t)(dm * 16 + lr)) * 256 + lq * 8 + ks * 32);
            acc[dm] = __builtin_amdgcn_mfma_f32_16x16x32_bf16(a, bfrag, acc[dm], 0, 0, 0);
        }
    }

    const int node = r0 + lr;
    float ps = 0.f, pd = 0.f;
    #pragma unroll
    for (int dm = 0; dm < 4; dm++) {
        const int d0 = dm * 16 + lq * 4;
        float4 bi = *(const float4*)(b2 + d0);
        float4 as = *(const float4*)(a2 + d0);
        float4 ad = *(const float4*)(a2 + 64 + d0);
        ushort4 st; float vv;
        vv = acc[dm][0] + bi.x; st.x = f2bf(vv); ps = fmaf(vv, as.x, ps); pd = fmaf(vv, ad.x, pd);
        vv = acc[dm][1] + bi.y; st.y = f2bf(vv); ps = fmaf(vv, as.y, ps); pd = fmaf(vv, ad.y, pd);
        vv = acc[dm][2] + bi.z; st.z = f2bf(vv); ps = fmaf(vv, as.z, ps); pd = fmaf(vv, ad.z, pd);
        vv = acc[dm][3] + bi.w; st.w = f2bf(vv); ps = fmaf(vv, as.w, ps); pd = fmaf(vv, ad.w, pd);
        *(ushort4*)(z2c + (size_t)node * 64 + d0) = st;
    }
    ps += __shfl_xor(ps, 16); ps += __shfl_xor(ps, 32);
    pd += __shfl_xor(pd, 16); pd += __shfl_xor(pd, 32);
    if (lq == 0) { s2s[node] = f2bf(ps); s2d[node] = f2bf(pd); }
}

// ---------------- gi GEMM -> node-blocked gib2[b][n][c][t] ----------------
__global__ __launch_bounds__(256) void k_mgi(
    const unsigned short* __restrict__ h2b, const unsigned short* __restrict__ WihB,
    const float* __restrict__ bih, unsigned short* __restrict__ gib2)
{
    const int tid = threadIdx.x, w = tid >> 6, l = tid & 63;
    const int lr = l & 15, lq = l >> 4;
    const int r0 = blockIdx.x * 64 + w * 16;
    const int col0 = blockIdx.y * 64;

    const int rA = r0 + lr;
    const int bA = rA / 16000;
    const int remA = rA - bA * 16000;
    const int nAr = remA >> 3, tA = remA & 7;
    const unsigned short* Ab = h2b + ((size_t)((bA * 8 + tA) * 2000) + nAr) * 64 + lq * 8;

    f4v acc[4] = {};
    #pragma unroll
    for (int ks = 0; ks < 2; ks++) {
        s8v a = *(const s8v*)(Ab + ks * 32);
        #pragma unroll
        for (int nt = 0; nt < 4; nt++) {
            s8v bfr = *(const s8v*)(WihB + ((size_t)(col0 + nt * 16 + lr)) * 64 + lq * 8 + ks * 32);
            acc[nt] = __builtin_amdgcn_mfma_f32_16x16x32_bf16(a, bfr, acc[nt], 0, 0, 0);
        }
    }
    const int rrb = r0 + lq * 4;
    const int bO = rrb / 16000;
    const int remO = rrb - bO * 16000;
    const int nO = remO >> 3, tO = remO & 7;
    #pragma unroll
    for (int nt = 0; nt < 4; nt++) {
        int cc = col0 + nt * 16 + lr;
        float bias = bih[cc];
        ushort4 st;
        st.x = f2bf(acc[nt][0] + bias); st.y = f2bf(acc[nt][1] + bias);
        st.z = f2bf(acc[nt][2] + bias); st.w = f2bf(acc[nt][3] + bias);
        *(ushort4*)(gib2 + (((size_t)(bO * 2000 + nO)) * 192 + cc) * 8 + tO) = st;
    }
}

// ---------------- fused edge-softmax + aggregation + ELU, 8 rows/wave, XCD swizzle ----------------
// Phase 1: lane (rw=l>>3, k=l&7) owns edge (row rw, neighbor k): softmax via 8-lane shfl_xor.
// Phase 2: all 64 lanes gather z and accumulate; alpha/index broadcast by readlane.
__global__ void k_agg(const unsigned short* __restrict__ z, const unsigned short* __restrict__ ssrc,
                      const unsigned short* __restrict__ sdst, const float* __restrict__ ab,
                      const int* __restrict__ src, unsigned short* __restrict__ out,
                      int Hn, int outStride)
{
    const int blk = (blockIdx.x & 7) * ((int)gridDim.x >> 3) + (blockIdx.x >> 3);
    const int wv = threadIdx.x >> 6, lane = threadIdx.x & 63;
    const int rbase = blk * 32 + wv * 8;            // 8 rows, same bth (2000%8==0)
    const int bth = rbase / 2000;
    const int n0 = rbase - bth * 2000;
    const size_t zb = (size_t)bth * 2000;
    const int h = bth % Hn;

    // ---- phase 1: per-edge softmax (one edge per lane) ----
    const int rw_ = lane >> 3, k_ = lane & 7;
    const int sidx = src[(n0 + rw_) * 8 + k_];                 // coalesced dword
    float e = bf2f(ssrc[zb + sidx]) + bf2f(sdst[rbase + rw_]) + ab[h];
    e = e > 0.f ? e : 0.01f * e;                               // leaky_relu
    float m = e;
    m = fmaxf(m, __shfl_xor(m, 1)); m = fmaxf(m, __shfl_xor(m, 2)); m = fmaxf(m, __shfl_xor(m, 4));
    float ex = __expf(e - m);
    float sm = ex;
    sm += __shfl_xor(sm, 1); sm += __shfl_xor(sm, 2); sm += __shfl_xor(sm, 4);
    const float al = ex / sm;

    // ---- phase 2: gather + weighted sum ----
    unsigned short zsv[8][8];
    #pragma unroll
    for (int rw = 0; rw < 8; rw++)
        #pragma unroll
        for (int k = 0; k < 8; k++) {
            int si_b = __shfl(sidx, rw * 8 + k);
            zsv[rw][k] = z[(zb + si_b) * 64 + lane];
        }
    #pragma unroll
    for (int rw = 0; rw < 8; rw++) {
        float acc = 0.f;
        #pragma unroll
        for (int k = 0; k < 8; k++) {
            float a_b = __shfl(al, rw * 8 + k);
            acc = fmaf(a_b, bf2f(zsv[rw][k]), acc);
        }
        acc = acc > 0.f ? acc : (__expf(acc) - 1.f);           // ELU
        int btl = bth / Hn;
        out[((size_t)btl * N_ + n0 + rw) * outStride + h * 64 + lane] = f2bf(acc);
    }
}

// ---------------- MFMA GRU: 250 blocks, TWO chain-groups, warm 2 nodes ----------------
__global__ __launch_bounds__(256) void k_gru(
    const unsigned short* __restrict__ gib2, const unsigned short* __restrict__ WhhB,
    const float* __restrict__ bhh, const float* __restrict__ h0,
    float* __restrict__ hloc)
{
    const int q = blockIdx.x;                 // [0,250)
    const int tid = threadIdx.x;
    const int w = tid >> 6, l = tid & 63;
    const int lr = l & 15, lq = l >> 4;
    const int j0 = w * 16 + lq * 4;
    const int bb = lr & 7;                    // batch
    const int grp = lr >> 3;                  // chain group 0/1
    const int Q = q + grp * 250;              // chain id [0,500)

    __shared__ unsigned short hbuf[3][16][72];
    {
        unsigned int* p = (unsigned int*)hbuf;
        #pragma unroll 1
        for (int i = tid; i < 3 * 16 * 72 / 2; i += 256) p[i] = 0u;
    }
    __syncthreads();

    const int jrow = w * 16 + lr;
    s8v wR0 = *(const s8v*)(WhhB + (size_t)jrow * 64 + lq * 8);
    s8v wR1 = *(const s8v*)(WhhB + (size_t)jrow * 64 + 32 + lq * 8);
    s8v wZ0 = *(const s8v*)(WhhB + (size_t)(64 + jrow) * 64 + lq * 8);
    s8v wZ1 = *(const s8v*)(WhhB + (size_t)(64 + jrow) * 64 + 32 + lq * 8);
    s8v wN0 = *(const s8v*)(WhhB + (size_t)(128 + jrow) * 64 + lq * 8);
    s8v wN1 = *(const s8v*)(WhhB + (size_t)(128 + jrow) * 64 + 32 + lq * 8);

    float4 t4;
    t4 = *(const float4*)(bhh + j0);        float bhr_[4] = {t4.x, t4.y, t4.z, t4.w};
    t4 = *(const float4*)(bhh + 64 + j0);   float bhz_[4] = {t4.x, t4.y, t4.z, t4.w};
    t4 = *(const float4*)(bhh + 128 + j0);  float bhn_[4] = {t4.x, t4.y, t4.z, t4.w};

    float hp[4] = {0.f, 0.f, 0.f, 0.f};
    if (Q == 0) {
        float4 h04 = *(const float4*)(h0 + bb * 64 + j0);
        hp[0] = h04.x; hp[1] = h04.y; hp[2] = h04.z; hp[3] = h04.w;
        ushort4 st;
        st.x = f2bf(hp[0]); st.y = f2bf(hp[1]); st.z = f2bf(hp[2]); st.w = f2bf(hp[3]);
        *(ushort4*)&hbuf[0][lr][j0] = st;
    }
    __syncthreads();

    const unsigned short* gbase = gib2 + ((size_t)bb * 2000) * 192 * 8;
    const int ndF = Q * 4 - 2;                // warm 2 nodes (16 steps)

    int ndc = ndF < 0 ? 0 : ndF;
    u8v cRv[4], cZv[4], cNv[4];
    #pragma unroll
    for (int rg = 0; rg < 4; rg++) {
        cRv[rg] = *(const u8v*)(gbase + (((size_t)ndc * 192 + j0 + rg)) * 8);
        cZv[rg] = *(const u8v*)(gbase + (((size_t)ndc * 192 + 64 + j0 + rg)) * 8);
        cNv[rg] = *(const u8v*)(gbase + (((size_t)ndc * 192 + 128 + j0 + rg)) * 8);
    }

    int sb = 0;
    for (int o = 0; o < 6; ++o) {
        const int nd = ndF + o;
        u8v nRv[4] = {}, nZv[4] = {}, nNv[4] = {};
        if (o < 5) {
            int ndn = nd + 1; if (ndn < 0) ndn = 0;
            #pragma unroll
            for (int rg = 0; rg < 4; rg++) {
                nRv[rg] = *(const u8v*)(gbase + (((size_t)ndn * 192 + j0 + rg)) * 8);
                nZv[rg] = *(const u8v*)(gbase + (((size_t)ndn * 192 + 64 + j0 + rg)) * 8);
                nNv[rg] = *(const u8v*)(gbase + (((size_t)ndn * 192 + 128 + j0 + rg)) * 8);
            }
        }
        #pragma unroll
        for (int ts = 0; ts < 8; ts++) {
            const unsigned short* hbp = &hbuf[sb][lr][0];
            s8v hb0 = *(const s8v*)(hbp + lq * 8);
            s8v hb1 = *(const s8v*)(hbp + 32 + lq * 8);

            f4v aR = {}, aZ = {}, aN = {};
            aR = __builtin_amdgcn_mfma_f32_16x16x32_bf16(wR0, hb0, aR, 0, 0, 0);
            aR = __builtin_amdgcn_mfma_f32_16x16x32_bf16(wR1, hb1, aR, 0, 0, 0);
            aZ = __builtin_amdgcn_mfma_f32_16x16x32_bf16(wZ0, hb0, aZ, 0, 0, 0);
            aZ = __builtin_amdgcn_mfma_f32_16x16x32_bf16(wZ1, hb1, aZ, 0, 0, 0);
            aN = __builtin_amdgcn_mfma_f32_16x16x32_bf16(wN0, hb0, aN, 0, 0, 0);
            aN = __builtin_amdgcn_mfma_f32_16x16x32_bf16(wN1, hb1, aN, 0, 0, 0);

            #pragma unroll
            for (int rg = 0; rg < 4; rg++) {
                float gr = bf2f((unsigned short)cRv[rg][ts]);
                float gz = bf2f((unsigned short)cZv[rg][ts]);
                float gn = bf2f((unsigned short)cNv[rg][ts]);
                float rr = 1.f / (1.f + __expf(-(gr + aR[rg] + bhr_[rg])));
                float zz = 1.f / (1.f + __expf(-(gz + aZ[rg] + bhz_[rg])));
                float tn = gn + rr * (aN[rg] + bhn_[rg]);
                float nn = 1.f - 2.f / (__expf(2.f * tn) + 1.f);
                float hnew = (1.f - zz) * nn + zz * hp[rg];
                hp[rg] = (nd >= 0) ? hnew : hp[rg];
            }

            int nsb = sb + 1; if (nsb == 3) nsb = 0;
            ushort4 st;
            st.x = f2bf(hp[0]); st.y = f2bf(hp[1]);
            st.z = f2bf(hp[2]); st.w = f2bf(hp[3]);
            *(ushort4*)&hbuf[nsb][lr][j0] = st;
            if (ts == 7 && o >= 2) {
                float4 ov; ov.x = hp[0]; ov.y = hp[1]; ov.z = hp[2]; ov.w = hp[3];
                *(float4*)(hloc + ((size_t)nd * 8 + bb) * 64 + j0) = ov;
            }
            __syncthreads();
            sb = nsb;
        }
        #pragma unroll
        for (int rg = 0; rg < 4; rg++) {
            cRv[rg] = nRv[rg]; cZv[rg] = nZv[rg]; cNv[rg] = nNv[rg];
        }
    }
}

// ---------------- final projection ----------------
__global__ void k_proj(const float* __restrict__ hloc, const float* __restrict__ Wp,
                       const float* __restrict__ bp, float* __restrict__ out)
{
    int idx = blockIdx.x * 256 + threadIdx.x;   // 256000 total
    int p = idx & 15;
    int b = (idx >> 4) & 7;
    int n = idx >> 7;
    const float* hr = hloc + ((size_t)n * B_ + b) * 64;
    float acc = bp[p];
    #pragma unroll
    for (int jj = 0; jj < 64; jj++) acc = fmaf(hr[jj], Wp[jj * 16 + p], acc);
    out[((size_t)b * N_ + n) * PW_ + p] = acc;
}

extern "C" void kernel_launch(void* const* d_in, const int* in_sizes, int n_in,
                              void* d_out, int out_size, void* d_ws, size_t ws_size,
                              hipStream_t stream) {
    const float* dyn  = (const float*)d_in[0];
    const float* h0   = (const float*)d_in[1];
    const int*   src  = (const int*)  d_in[2];
    const float* W1   = (const float*)d_in[3];
    const float* b1   = (const float*)d_in[4];
    const float* a1   = (const float*)d_in[5];
    const float* a1b  = (const float*)d_in[6];
    const float* W2   = (const float*)d_in[7];
    const float* b2   = (const float*)d_in[8];
    const float* a2   = (const float*)d_in[9];
    const float* a2b  = (const float*)d_in[10];
    const float* Wih  = (const float*)d_in[11];
    const float* Whh  = (const float*)d_in[12];
    const float* bih  = (const float*)d_in[13];
    const float* bhh  = (const float*)d_in[14];
    const float* Wp   = (const float*)d_in[15];
    const float* bp   = (const float*)d_in[16];
    float* out = (float*)d_out;

    // Workspace: R7-proven layout, peak 133,267,456 B.
    char* w = (char*)d_ws;
    unsigned short* z1c  = (unsigned short*)(w);                  // 65,536,000
    unsigned short* h1c  = (unsigned short*)(w + 65536000);       // 65,536,000
    unsigned short* s1s  = (unsigned short*)(w + 131072000);      //  1,024,000 (bf16)
    unsigned short* s1d  = (unsigned short*)(w + 132096000);      //  1,024,000
    unsigned short* W1T  = (unsigned short*)(w + 133120000);      //     65,536
    unsigned short* W2T  = (unsigned short*)(w + 133185536);      //     32,768
    unsigned short* WihB = (unsigned short*)(w + 133218304);      //     24,576
    unsigned short* WhhB = (unsigned short*)(w + 133242880);      //     24,576 -> 133,267,456
    unsigned short* z2c  = (unsigned short*)(w);                  // 16,384,000 (over dead z1c)
    unsigned short* s2s  = (unsigned short*)(w + 16384000);       //    256,000
    unsigned short* s2d  = (unsigned short*)(w + 16640000);       //    256,000
    unsigned short* h2b  = (unsigned short*)(w + 16896000);       // 16,384,000
    float*          hloc = (float*)        (w + 33280000);        //  4,096,000
    unsigned short* gib2 = (unsigned short*)(w + 65536000);       // 49,152,000 (over dead h1c)

    k_cvt_w<<<288, 256, 0, stream>>>(W1, W2, Wih, Whh, W1T, W2T, WihB, WhhB);

    // Single-chunk GAT pipeline, 8 dispatches total
    k_mz1<<<2000, 256, 0, stream>>>(dyn, W1T, b1, a1, z1c, s1s, s1d);
    k_agg<<<16000, 256, 0, stream>>>(z1c, s1s, s1d, a1b, src, h1c, H_, 256);
    k_mz2<<<2000, 256, 0, stream>>>(h1c, W2T, b2, a2, z2c, s2s, s2d);
    k_agg<<<4000, 256, 0, stream>>>(z2c, s2s, s2d, a2b, src, h2b, 1, 64);

    k_mgi<<<dim3(2000, 3), 256, 0, stream>>>(h2b, WihB, bih, gib2);
    k_gru<<<250, 256, 0, stream>>>(gib2, WhhB, bhh, h0, hloc);
    k_proj<<<1000, 256, 0, stream>>>(hloc, Wp, bp, out);
}

// Round 10
// 375.501 us; speedup vs baseline: 1.6467x; 1.1969x over previous
//
#include <hip/hip_runtime.h>

// Problem constants
#define B_ 8
#define N_ 2000
#define T_ 8
#define F_ 128
#define DEG_ 8
#define H_ 4
#define G_ 64
#define PW_ 16
#define SEQ_ (N_ * T_)   // 16000

typedef short s8v __attribute__((ext_vector_type(8)));            // 8 bf16
typedef unsigned short u8v __attribute__((ext_vector_type(8)));   // 8 bf16 (loads)
typedef float f4v __attribute__((ext_vector_type(4)));            // MFMA acc

static __device__ __forceinline__ unsigned short f2bf(float f) {
    unsigned int u = __float_as_uint(f);
    u += 0x7FFFu + ((u >> 16) & 1u);         // RNE
    return (unsigned short)(u >> 16);
}
static __device__ __forceinline__ float bf2f(unsigned short b) {
    return __uint_as_float(((unsigned int)b) << 16);
}
static __device__ __forceinline__ s8v pack8(float4 u, float4 v) {
    s8v r;
    r[0] = (short)f2bf(u.x); r[1] = (short)f2bf(u.y);
    r[2] = (short)f2bf(u.z); r[3] = (short)f2bf(u.w);
    r[4] = (short)f2bf(v.x); r[5] = (short)f2bf(v.y);
    r[6] = (short)f2bf(v.z); r[7] = (short)f2bf(v.w);
    return r;
}

// ---------------- weight prep: W1T[h][d][f], W2T[d][k], WihB[j][k], WhhB (bf16) ----------------
__global__ void k_cvt_w(const float* __restrict__ W1, const float* __restrict__ W2,
                        const float* __restrict__ Wih, const float* __restrict__ Whh,
                        unsigned short* __restrict__ W1T, unsigned short* __restrict__ W2T,
                        unsigned short* __restrict__ WihB, unsigned short* __restrict__ WhhB)
{
    int idx = blockIdx.x * 256 + threadIdx.x;      // 73,728 total
    if (idx < 32768) {                              // W1 (4,128,64) -> [h][d][f]
        int h = idx >> 13, rem = idx & 8191;
        int d = rem >> 7, f = rem & 127;
        W1T[idx] = f2bf(W1[h * 8192 + f * 64 + d]);
    } else if (idx < 49152) {                       // W2 (256,64) -> [d][k]
        int i = idx - 32768;
        int d = i >> 8, k = i & 255;
        W2T[i] = f2bf(W2[k * 64 + d]);
    } else if (idx < 61440) {                       // Wih (192,64) straight
        int i = idx - 49152;
        WihB[i] = f2bf(Wih[i]);
    } else if (idx < 73728) {                       // Whh (192,64) straight
        int i = idx - 61440;
        WhhB[i] = f2bf(Whh[i]);
    }
}

// ---------------- z1 GEMM (A=W1T, B=activations) + fused scores (bf16, single chunk) ----------------
__global__ __launch_bounds__(256) void k_mz1(
    const float* __restrict__ dyn, const unsigned short* __restrict__ W1T,
    const float* __restrict__ b1, const float* __restrict__ a1,
    unsigned short* __restrict__ z1c, unsigned short* __restrict__ s1s,
    unsigned short* __restrict__ s1d)
{
    const int tid = threadIdx.x, w = tid >> 6, l = tid & 63;
    const int lr = l & 15, lq = l >> 4;
    const int r0 = blockIdx.x * 64 + w * 16;       // row strip over 64*2000 rows
    const int btl = r0 / 2000, n0 = r0 - btl * 2000;
    const int b = btl >> 3, t = btl & 7;

    const float* Bp = dyn + (((size_t)(b * 2000) + n0 + lr) * 8 + t) * 128 + lq * 8;

    f4v acc[4][4] = {};
    #pragma unroll
    for (int ks = 0; ks < 4; ks++) {
        float4 u = *(const float4*)(Bp + ks * 32);
        float4 v = *(const float4*)(Bp + ks * 32 + 4);
        s8v bfrag = pack8(u, v);
        #pragma unroll
        for (int h = 0; h < 4; h++)
            #pragma unroll
            for (int dm = 0; dm < 4; dm++) {
                s8v a = *(const s8v*)(W1T + ((size_t)(h * 64 + dm * 16 + lr)) * 128 + lq * 8 + ks * 32);
                acc[h][dm] = __builtin_amdgcn_mfma_f32_16x16x32_bf16(a, bfrag, acc[h][dm], 0, 0, 0);
            }
    }

    const int node = n0 + lr;
    #pragma unroll
    for (int h = 0; h < 4; h++) {
        const size_t zrow = (size_t)(btl * 4 + h) * 2000 + node;
        float ps = 0.f, pd = 0.f;
        #pragma unroll
        for (int dm = 0; dm < 4; dm++) {
            const int d0 = dm * 16 + lq * 4;
            float4 bi = *(const float4*)(b1 + h * 64 + d0);
            float4 as = *(const float4*)(a1 + h * 128 + d0);
            float4 ad = *(const float4*)(a1 + h * 128 + 64 + d0);
            ushort4 st; float vv;
            vv = acc[h][dm][0] + bi.x; st.x = f2bf(vv); ps = fmaf(vv, as.x, ps); pd = fmaf(vv, ad.x, pd);
            vv = acc[h][dm][1] + bi.y; st.y = f2bf(vv); ps = fmaf(vv, as.y, ps); pd = fmaf(vv, ad.y, pd);
            vv = acc[h][dm][2] + bi.z; st.z = f2bf(vv); ps = fmaf(vv, as.z, ps); pd = fmaf(vv, ad.z, pd);
            vv = acc[h][dm][3] + bi.w; st.w = f2bf(vv); ps = fmaf(vv, as.w, ps); pd = fmaf(vv, ad.w, pd);
            *(ushort4*)(z1c + zrow * 64 + d0) = st;
        }
        ps += __shfl_xor(ps, 16); ps += __shfl_xor(ps, 32);
        pd += __shfl_xor(pd, 16); pd += __shfl_xor(pd, 32);
        if (lq == 0) { s1s[zrow] = f2bf(ps); s1d[zrow] = f2bf(pd); }
    }
}

// ---------------- z2 GEMM + fused scores. K=256 ----------------
__global__ __launch_bounds__(256) void k_mz2(
    const unsigned short* __restrict__ h1c, const unsigned short* __restrict__ W2T,
    const float* __restrict__ b2, const float* __restrict__ a2,
    unsigned short* __restrict__ z2c, unsigned short* __restrict__ s2s,
    unsigned short* __restrict__ s2d)
{
    const int tid = threadIdx.x, w = tid >> 6, l = tid & 63;
    const int lr = l & 15, lq = l >> 4;
    const int r0 = blockIdx.x * 64 + w * 16;

    const unsigned short* Bp = h1c + (size_t)(r0 + lr) * 256 + lq * 8;

    f4v acc[4] = {};
    #pragma unroll
    for (int ks = 0; ks < 8; ks++) {
        s8v bfrag = *(const s8v*)(Bp + ks * 32);
        #pragma unroll
        for (int dm = 0; dm < 4; dm++) {
            s8v a = *(const s8v*)(W2T + ((size_t)(dm * 16 + lr)) * 256 + lq * 8 + ks * 32);
            acc[dm] = __builtin_amdgcn_mfma_f32_16x16x32_bf16(a, bfrag, acc[dm], 0, 0, 0);
        }
    }

    const int node = r0 + lr;
    float ps = 0.f, pd = 0.f;
    #pragma unroll
    for (int dm = 0; dm < 4; dm++) {
        const int d0 = dm * 16 + lq * 4;
        float4 bi = *(const float4*)(b2 + d0);
        float4 as = *(const float4*)(a2 + d0);
        float4 ad = *(const float4*)(a2 + 64 + d0);
        ushort4 st; float vv;
        vv = acc[dm][0] + bi.x; st.x = f2bf(vv); ps = fmaf(vv, as.x, ps); pd = fmaf(vv, ad.x, pd);
        vv = acc[dm][1] + bi.y; st.y = f2bf(vv); ps = fmaf(vv, as.y, ps); pd = fmaf(vv, ad.y, pd);
        vv = acc[dm][2] + bi.z; st.z = f2bf(vv); ps = fmaf(vv, as.z, ps); pd = fmaf(vv, ad.z, pd);
        vv = acc[dm][3] + bi.w; st.w = f2bf(vv); ps = fmaf(vv, as.w, ps); pd = fmaf(vv, ad.w, pd);
        *(ushort4*)(z2c + (size_t)node * 64 + d0) = st;
    }
    ps += __shfl_xor(ps, 16); ps += __shfl_xor(ps, 32);
    pd += __shfl_xor(pd, 16); pd += __shfl_xor(pd, 32);
    if (lq == 0) { s2s[node] = f2bf(ps); s2d[node] = f2bf(pd); }
}

// ---------------- gi GEMM -> node-blocked gib2[b][n][c][t] ----------------
__global__ __launch_bounds__(256) void k_mgi(
    const unsigned short* __restrict__ h2b, const unsigned short* __restrict__ WihB,
    const float* __restrict__ bih, unsigned short* __restrict__ gib2)
{
    const int tid = threadIdx.x, w = tid >> 6, l = tid & 63;
    const int lr = l & 15, lq = l >> 4;
    const int r0 = blockIdx.x * 64 + w * 16;
    const int col0 = blockIdx.y * 64;

    const int rA = r0 + lr;
    const int bA = rA / 16000;
    const int remA = rA - bA * 16000;
    const int nAr = remA >> 3, tA = remA & 7;
    const unsigned short* Ab = h2b + ((size_t)((bA * 8 + tA) * 2000) + nAr) * 64 + lq * 8;

    f4v acc[4] = {};
    #pragma unroll
    for (int ks = 0; ks < 2; ks++) {
        s8v a = *(const s8v*)(Ab + ks * 32);
        #pragma unroll
        for (int nt = 0; nt < 4; nt++) {
            s8v bfr = *(const s8v*)(WihB + ((size_t)(col0 + nt * 16 + lr)) * 64 + lq * 8 + ks * 32);
            acc[nt] = __builtin_amdgcn_mfma_f32_16x16x32_bf16(a, bfr, acc[nt], 0, 0, 0);
        }
    }
    const int rrb = r0 + lq * 4;
    const int bO = rrb / 16000;
    const int remO = rrb - bO * 16000;
    const int nO = remO >> 3, tO = remO & 7;
    #pragma unroll
    for (int nt = 0; nt < 4; nt++) {
        int cc = col0 + nt * 16 + lr;
        float bias = bih[cc];
        ushort4 st;
        st.x = f2bf(acc[nt][0] + bias); st.y = f2bf(acc[nt][1] + bias);
        st.z = f2bf(acc[nt][2] + bias); st.w = f2bf(acc[nt][3] + bias);
        *(ushort4*)(gib2 + (((size_t)(bO * 2000 + nO)) * 192 + cc) * 8 + tO) = st;
    }
}

// ---------------- fused edge-softmax + aggregation + ELU, 8 rows/wave, wide gathers ----------------
// Phase 1: lane (rw=l>>3, k=l&7) owns edge -> alpha via 8-lane shfl_xor softmax.
// Phase 2: lane (rw=l>>3, sub=l&7); per k one dwordx4 gather fetches 8 rows (16B/lane);
//          index/alpha broadcast via 1 shfl each; 8-float accumulator; 1 dwordx4 store.
__global__ void k_agg(const unsigned short* __restrict__ z, const unsigned short* __restrict__ ssrc,
                      const unsigned short* __restrict__ sdst, const float* __restrict__ ab,
                      const int* __restrict__ src, unsigned short* __restrict__ out,
                      int Hn, int outStride)
{
    const int blk = (blockIdx.x & 7) * ((int)gridDim.x >> 3) + (blockIdx.x >> 3);
    const int wv = threadIdx.x >> 6, lane = threadIdx.x & 63;
    const int rbase = blk * 32 + wv * 8;            // 8 rows, same bth (2000%8==0)
    const int bth = rbase / 2000;
    const int n0 = rbase - bth * 2000;
    const size_t zb = (size_t)bth * 2000;
    const int h = bth % Hn;

    // ---- phase 1: per-edge softmax (one edge per lane) ----
    const int rw_ = lane >> 3, k_ = lane & 7;
    const int sidx = src[(n0 + rw_) * 8 + k_];                 // coalesced dword
    float e = bf2f(ssrc[zb + sidx]) + bf2f(sdst[rbase + rw_]) + ab[h];
    e = e > 0.f ? e : 0.01f * e;                               // leaky_relu
    float m = e;
    m = fmaxf(m, __shfl_xor(m, 1)); m = fmaxf(m, __shfl_xor(m, 2)); m = fmaxf(m, __shfl_xor(m, 4));
    float ex = __expf(e - m);
    float sm = ex;
    sm += __shfl_xor(sm, 1); sm += __shfl_xor(sm, 2); sm += __shfl_xor(sm, 4);
    const float al = ex / sm;

    // ---- phase 2: wide gathers. lane = rw*8 + sub ----
    const int sub = lane & 7;                       // d-chunk within the row
    const int base8 = lane & 56;                    // rw*8
    float acc[8] = {0.f, 0.f, 0.f, 0.f, 0.f, 0.f, 0.f, 0.f};
    #pragma unroll
    for (int k = 0; k < 8; k++) {
        int row = __shfl(sidx, base8 | k);          // this rw's k-th neighbor
        float a_b = __shfl(al, base8 | k);
        u8v zv = *(const u8v*)(z + (zb + row) * 64 + sub * 8);   // 16B/lane, 8 rows/instr
        #pragma unroll
        for (int j = 0; j < 8; j++)
            acc[j] = fmaf(a_b, bf2f((unsigned short)zv[j]), acc[j]);
    }
    u8v ov;
    #pragma unroll
    for (int j = 0; j < 8; j++) {
        float v = acc[j];
        v = v > 0.f ? v : (__expf(v) - 1.f);        // ELU
        ov[j] = f2bf(v);
    }
    const int btl = bth / Hn;
    const int rw2 = lane >> 3;
    *(u8v*)(out + ((size_t)btl * N_ + n0 + rw2) * outStride + h * 64 + sub * 8) = ov;
}

// ---------------- MFMA GRU: 250 blocks, TWO chain-groups, warm 2 nodes ----------------
__global__ __launch_bounds__(256) void k_gru(
    const unsigned short* __restrict__ gib2, const unsigned short* __restrict__ WhhB,
    const float* __restrict__ bhh, const float* __restrict__ h0,
    float* __restrict__ hloc)
{
    const int q = blockIdx.x;                 // [0,250)
    const int tid = threadIdx.x;
    const int w = tid >> 6, l = tid & 63;
    const int lr = l & 15, lq = l >> 4;
    const int j0 = w * 16 + lq * 4;
    const int bb = lr & 7;                    // batch
    const int grp = lr >> 3;                  // chain group 0/1
    const int Q = q + grp * 250;              // chain id [0,500)

    __shared__ unsigned short hbuf[3][16][72];
    {
        unsigned int* p = (unsigned int*)hbuf;
        #pragma unroll 1
        for (int i = tid; i < 3 * 16 * 72 / 2; i += 256) p[i] = 0u;
    }
    __syncthreads();

    const int jrow = w * 16 + lr;
    s8v wR0 = *(const s8v*)(WhhB + (size_t)jrow * 64 + lq * 8);
    s8v wR1 = *(const s8v*)(WhhB + (size_t)jrow * 64 + 32 + lq * 8);
    s8v wZ0 = *(const s8v*)(WhhB + (size_t)(64 + jrow) * 64 + lq * 8);
    s8v wZ1 = *(const s8v*)(WhhB + (size_t)(64 + jrow) * 64 + 32 + lq * 8);
    s8v wN0 = *(const s8v*)(WhhB + (size_t)(128 + jrow) * 64 + lq * 8);
    s8v wN1 = *(const s8v*)(WhhB + (size_t)(128 + jrow) * 64 + 32 + lq * 8);

    float4 t4;
    t4 = *(const float4*)(bhh + j0);        float bhr_[4] = {t4.x, t4.y, t4.z, t4.w};
    t4 = *(const float4*)(bhh + 64 + j0);   float bhz_[4] = {t4.x, t4.y, t4.z, t4.w};
    t4 = *(const float4*)(bhh + 128 + j0);  float bhn_[4] = {t4.x, t4.y, t4.z, t4.w};

    float hp[4] = {0.f, 0.f, 0.f, 0.f};
    if (Q == 0) {
        float4 h04 = *(const float4*)(h0 + bb * 64 + j0);
        hp[0] = h04.x; hp[1] = h04.y; hp[2] = h04.z; hp[3] = h04.w;
        ushort4 st;
        st.x = f2bf(hp[0]); st.y = f2bf(hp[1]); st.z = f2bf(hp[2]); st.w = f2bf(hp[3]);
        *(ushort4*)&hbuf[0][lr][j0] = st;
    }
    __syncthreads();

    const unsigned short* gbase = gib2 + ((size_t)bb * 2000) * 192 * 8;
    const int ndF = Q * 4 - 2;                // warm 2 nodes (16 steps)

    int ndc = ndF < 0 ? 0 : ndF;
    u8v cRv[4], cZv[4], cNv[4];
    #pragma unroll
    for (int rg = 0; rg < 4; rg++) {
        cRv[rg] = *(const u8v*)(gbase + (((size_t)ndc * 192 + j0 + rg)) * 8);
        cZv[rg] = *(const u8v*)(gbase + (((size_t)ndc * 192 + 64 + j0 + rg)) * 8);
        cNv[rg] = *(const u8v*)(gbase + (((size_t)ndc * 192 + 128 + j0 + rg)) * 8);
    }

    int sb = 0;
    for (int o = 0; o < 6; ++o) {
        const int nd = ndF + o;
        u8v nRv[4] = {}, nZv[4] = {}, nNv[4] = {};
        if (o < 5) {
            int ndn = nd + 1; if (ndn < 0) ndn = 0;
            #pragma unroll
            for (int rg = 0; rg < 4; rg++) {
                nRv[rg] = *(const u8v*)(gbase + (((size_t)ndn * 192 + j0 + rg)) * 8);
                nZv[rg] = *(const u8v*)(gbase + (((size_t)ndn * 192 + 64 + j0 + rg)) * 8);
                nNv[rg] = *(const u8v*)(gbase + (((size_t)ndn * 192 + 128 + j0 + rg)) * 8);
            }
        }
        #pragma unroll
        for (int ts = 0; ts < 8; ts++) {
            const unsigned short* hbp = &hbuf[sb][lr][0];
            s8v hb0 = *(const s8v*)(hbp + lq * 8);
            s8v hb1 = *(const s8v*)(hbp + 32 + lq * 8);

            f4v aR = {}, aZ = {}, aN = {};
            aR = __builtin_amdgcn_mfma_f32_16x16x32_bf16(wR0, hb0, aR, 0, 0, 0);
            aR = __builtin_amdgcn_mfma_f32_16x16x32_bf16(wR1, hb1, aR, 0, 0, 0);
            aZ = __builtin_amdgcn_mfma_f32_16x16x32_bf16(wZ0, hb0, aZ, 0, 0, 0);
            aZ = __builtin_amdgcn_mfma_f32_16x16x32_bf16(wZ1, hb1, aZ, 0, 0, 0);
            aN = __builtin_amdgcn_mfma_f32_16x16x32_bf16(wN0, hb0, aN, 0, 0, 0);
            aN = __builtin_amdgcn_mfma_f32_16x16x32_bf16(wN1, hb1, aN, 0, 0, 0);

            #pragma unroll
            for (int rg = 0; rg < 4; rg++) {
                float gr = bf2f((unsigned short)cRv[rg][ts]);
                float gz = bf2f((unsigned short)cZv[rg][ts]);
                float gn = bf2f((unsigned short)cNv[rg][ts]);
                float rr = 1.f / (1.f + __expf(-(gr + aR[rg] + bhr_[rg])));
                float zz = 1.f / (1.f + __expf(-(gz + aZ[rg] + bhz_[rg])));
                float tn = gn + rr * (aN[rg] + bhn_[rg]);
                float nn = 1.f - 2.f / (__expf(2.f * tn) + 1.f);
                float hnew = (1.f - zz) * nn + zz * hp[rg];
                hp[rg] = (nd >= 0) ? hnew : hp[rg];
            }

            int nsb = sb + 1; if (nsb == 3) nsb = 0;
            ushort4 st;
            st.x = f2bf(hp[0]); st.y = f2bf(hp[1]);
            st.z = f2bf(hp[2]); st.w = f2bf(hp[3]);
            *(ushort4*)&hbuf[nsb][lr][j0] = st;
            if (ts == 7 && o >= 2) {
                float4 ov; ov.x = hp[0]; ov.y = hp[1]; ov.z = hp[2]; ov.w = hp[3];
                *(float4*)(hloc + ((size_t)nd * 8 + bb) * 64 + j0) = ov;
            }
            __syncthreads();
            sb = nsb;
        }
        #pragma unroll
        for (int rg = 0; rg < 4; rg++) {
            cRv[rg] = nRv[rg]; cZv[rg] = nZv[rg]; cNv[rg] = nNv[rg];
        }
    }
}

// ---------------- final projection ----------------
__global__ void k_proj(const float* __restrict__ hloc, const float* __restrict__ Wp,
                       const float* __restrict__ bp, float* __restrict__ out)
{
    int idx = blockIdx.x * 256 + threadIdx.x;   // 256000 total
    int p = idx & 15;
    int b = (idx >> 4) & 7;
    int n = idx >> 7;
    const float* hr = hloc + ((size_t)n * B_ + b) * 64;
    float acc = bp[p];
    #pragma unroll
    for (int jj = 0; jj < 64; jj++) acc = fmaf(hr[jj], Wp[jj * 16 + p], acc);
    out[((size_t)b * N_ + n) * PW_ + p] = acc;
}

extern "C" void kernel_launch(void* const* d_in, const int* in_sizes, int n_in,
                              void* d_out, int out_size, void* d_ws, size_t ws_size,
                              hipStream_t stream) {
    const float* dyn  = (const float*)d_in[0];
    const float* h0   = (const float*)d_in[1];
    const int*   src  = (const int*)  d_in[2];
    const float* W1   = (const float*)d_in[3];
    const float* b1   = (const float*)d_in[4];
    const float* a1   = (const float*)d_in[5];
    const float* a1b  = (const float*)d_in[6];
    const float* W2   = (const float*)d_in[7];
    const float* b2   = (const float*)d_in[8];
    const float* a2   = (const float*)d_in[9];
    const float* a2b  = (const float*)d_in[10];
    const float* Wih  = (const float*)d_in[11];
    const float* Whh  = (const float*)d_in[12];
    const float* bih  = (const float*)d_in[13];
    const float* bhh  = (const float*)d_in[14];
    const float* Wp   = (const float*)d_in[15];
    const float* bp   = (const float*)d_in[16];
    float* out = (float*)d_out;

    // Workspace: R7-proven layout, peak 133,267,456 B.
    char* w = (char*)d_ws;
    unsigned short* z1c  = (unsigned short*)(w);                  // 65,536,000
    unsigned short* h1c  = (unsigned short*)(w + 65536000);       // 65,536,000
    unsigned short* s1s  = (unsigned short*)(w + 131072000);      //  1,024,000 (bf16)
    unsigned short* s1d  = (unsigned short*)(w + 132096000);      //  1,024,000
    unsigned short* W1T  = (unsigned short*)(w + 133120000);      //     65,536
    unsigned short* W2T  = (unsigned short*)(w + 133185536);      //     32,768
    unsigned short* WihB = (unsigned short*)(w + 133218304);      //     24,576
    unsigned short* WhhB = (unsigned short*)(w + 133242880);      //     24,576 -> 133,267,456
    unsigned short* z2c  = (unsigned short*)(w);                  // 16,384,000 (over dead z1c)
    unsigned short* s2s  = (unsigned short*)(w + 16384000);       //    256,000
    unsigned short* s2d  = (unsigned short*)(w + 16640000);       //    256,000
    unsigned short* h2b  = (unsigned short*)(w + 16896000);       // 16,384,000
    float*          hloc = (float*)        (w + 33280000);        //  4,096,000
    unsigned short* gib2 = (unsigned short*)(w + 65536000);       // 49,152,000 (over dead h1c)

    k_cvt_w<<<288, 256, 0, stream>>>(W1, W2, Wih, Whh, W1T, W2T, WihB, WhhB);

    // Single-chunk GAT pipeline, 8 dispatches total
    k_mz1<<<2000, 256, 0, stream>>>(dyn, W1T, b1, a1, z1c, s1s, s1d);
    k_agg<<<16000, 256, 0, stream>>>(z1c, s1s, s1d, a1b, src, h1c, H_, 256);
    k_mz2<<<2000, 256, 0, stream>>>(h1c, W2T, b2, a2, z2c, s2s, s2d);
    k_agg<<<4000, 256, 0, stream>>>(z2c, s2s, s2d, a2b, src, h2b, 1, 64);

    k_mgi<<<dim3(2000, 3), 256, 0, stream>>>(h2b, WihB, bih, gib2);
    k_gru<<<250, 256, 0, stream>>>(gib2, WhhB, bhh, h0, hloc);
    k_proj<<<1000, 256, 0, stream>>>(hloc, Wp, bp, out);
}

// Round 11
// 347.854 us; speedup vs baseline: 1.7776x; 1.0795x over previous
//
#include <hip/hip_runtime.h>

// Problem constants
#define B_ 8
#define N_ 2000
#define T_ 8
#define F_ 128
#define DEG_ 8
#define H_ 4
#define G_ 64
#define PW_ 16
#define SEQ_ (N_ * T_)   // 16000

typedef short s8v __attribute__((ext_vector_type(8)));            // 8 bf16
typedef unsigned short u8v __attribute__((ext_vector_type(8)));   // 8 bf16 (loads)
typedef float f4v __attribute__((ext_vector_type(4)));            // MFMA acc

static __device__ __forceinline__ unsigned short f2bf(float f) {
    unsigned int u = __float_as_uint(f);
    u += 0x7FFFu + ((u >> 16) & 1u);         // RNE
    return (unsigned short)(u >> 16);
}
static __device__ __forceinline__ float bf2f(unsigned short b) {
    return __uint_as_float(((unsigned int)b) << 16);
}
static __device__ __forceinline__ s8v pack8(float4 u, float4 v) {
    s8v r;
    r[0] = (short)f2bf(u.x); r[1] = (short)f2bf(u.y);
    r[2] = (short)f2bf(u.z); r[3] = (short)f2bf(u.w);
    r[4] = (short)f2bf(v.x); r[5] = (short)f2bf(v.y);
    r[6] = (short)f2bf(v.z); r[7] = (short)f2bf(v.w);
    return r;
}

// ---------------- weight prep: W1T[h][d][f], W2T[d][k], WihB[j][k], WhhB (bf16) ----------------
__global__ void k_cvt_w(const float* __restrict__ W1, const float* __restrict__ W2,
                        const float* __restrict__ Wih, const float* __restrict__ Whh,
                        unsigned short* __restrict__ W1T, unsigned short* __restrict__ W2T,
                        unsigned short* __restrict__ WihB, unsigned short* __restrict__ WhhB)
{
    int idx = blockIdx.x * 256 + threadIdx.x;      // 73,728 total
    if (idx < 32768) {                              // W1 (4,128,64) -> [h][d][f]
        int h = idx >> 13, rem = idx & 8191;
        int d = rem >> 7, f = rem & 127;
        W1T[idx] = f2bf(W1[h * 8192 + f * 64 + d]);
    } else if (idx < 49152) {                       // W2 (256,64) -> [d][k]
        int i = idx - 32768;
        int d = i >> 8, k = i & 255;
        W2T[i] = f2bf(W2[k * 64 + d]);
    } else if (idx < 61440) {                       // Wih (192,64) straight
        int i = idx - 49152;
        WihB[i] = f2bf(Wih[i]);
    } else if (idx < 73728) {                       // Whh (192,64) straight
        int i = idx - 61440;
        WhhB[i] = f2bf(Whh[i]);
    }
}

// ---------------- z1 GEMM: wave = head, weights register-resident, 8 strips w/ prefetch ----------------
// Block: 128 rows (8 strips of 16). Wave w holds head w's full A-operand (16 s8v = 64 VGPRs)
// and loops strips; dyn B-frags prefetched one strip ahead (L1-shared across the 4 waves).
__global__ __launch_bounds__(256) void k_mz1(
    const float* __restrict__ dyn, const unsigned short* __restrict__ W1T,
    const float* __restrict__ b1, const float* __restrict__ a1,
    unsigned short* __restrict__ z1c, unsigned short* __restrict__ s1s,
    unsigned short* __restrict__ s1d)
{
    const int tid = threadIdx.x, h = tid >> 6, l = tid & 63;
    const int lr = l & 15, lq = l >> 4;

    // persistent A-frags for this head: rows h*64 + dm*16 + lr, k = lq*8 + ks*32
    s8v wfr[4][4];
    #pragma unroll
    for (int dm = 0; dm < 4; dm++)
        #pragma unroll
        for (int ks = 0; ks < 4; ks++)
            wfr[dm][ks] = *(const s8v*)(W1T + ((size_t)(h * 64 + dm * 16 + lr)) * 128 + lq * 8 + ks * 32);

    const int rblk = blockIdx.x * 128;
    int btl = rblk / 2000;
    int n0 = rblk - btl * 2000;

    // prefetch strip 0
    float4 u[4], v[4];
    {
        const float* Bp = dyn + (((size_t)((btl >> 3) * 2000) + n0 + lr) * 8 + (btl & 7)) * 128 + lq * 8;
        #pragma unroll
        for (int ks = 0; ks < 4; ks++) {
            u[ks] = *(const float4*)(Bp + ks * 32);
            v[ks] = *(const float4*)(Bp + ks * 32 + 4);
        }
    }

    for (int s = 0; s < 8; s++) {
        s8v bf[4];
        #pragma unroll
        for (int ks = 0; ks < 4; ks++) bf[ks] = pack8(u[ks], v[ks]);

        const int cbtl = btl, cn0 = n0;
        if (s < 7) {                                 // prefetch next strip
            n0 += 16;
            if (n0 == 2000) { n0 = 0; btl++; }
            const float* Bp = dyn + (((size_t)((btl >> 3) * 2000) + n0 + lr) * 8 + (btl & 7)) * 128 + lq * 8;
            #pragma unroll
            for (int ks = 0; ks < 4; ks++) {
                u[ks] = *(const float4*)(Bp + ks * 32);
                v[ks] = *(const float4*)(Bp + ks * 32 + 4);
            }
        }

        f4v acc[4] = {};
        #pragma unroll
        for (int ks = 0; ks < 4; ks++)
            #pragma unroll
            for (int dm = 0; dm < 4; dm++)
                acc[dm] = __builtin_amdgcn_mfma_f32_16x16x32_bf16(wfr[dm][ks], bf[ks], acc[dm], 0, 0, 0);

        // epilogue: bias + z-store + fused scores (this head only)
        const int node = cn0 + lr;
        const size_t zrow = (size_t)(cbtl * 4 + h) * 2000 + node;
        float ps = 0.f, pd = 0.f;
        #pragma unroll
        for (int dm = 0; dm < 4; dm++) {
            const int d0 = dm * 16 + lq * 4;
            float4 bi = *(const float4*)(b1 + h * 64 + d0);
            float4 as = *(const float4*)(a1 + h * 128 + d0);
            float4 ad = *(const float4*)(a1 + h * 128 + 64 + d0);
            ushort4 st; float vv;
            vv = acc[dm][0] + bi.x; st.x = f2bf(vv); ps = fmaf(vv, as.x, ps); pd = fmaf(vv, ad.x, pd);
            vv = acc[dm][1] + bi.y; st.y = f2bf(vv); ps = fmaf(vv, as.y, ps); pd = fmaf(vv, ad.y, pd);
            vv = acc[dm][2] + bi.z; st.z = f2bf(vv); ps = fmaf(vv, as.z, ps); pd = fmaf(vv, ad.z, pd);
            vv = acc[dm][3] + bi.w; st.w = f2bf(vv); ps = fmaf(vv, as.w, ps); pd = fmaf(vv, ad.w, pd);
            *(ushort4*)(z1c + zrow * 64 + d0) = st;
        }
        ps += __shfl_xor(ps, 16); ps += __shfl_xor(ps, 32);
        pd += __shfl_xor(pd, 16); pd += __shfl_xor(pd, 32);
        if (lq == 0) { s1s[zrow] = f2bf(ps); s1d[zrow] = f2bf(pd); }
    }
}

// ---------------- z2 GEMM + fused scores. K=256 ----------------
__global__ __launch_bounds__(256) void k_mz2(
    const unsigned short* __restrict__ h1c, const unsigned short* __restrict__ W2T,
    const float* __restrict__ b2, const float* __restrict__ a2,
    unsigned short* __restrict__ z2c, unsigned short* __restrict__ s2s,
    unsigned short* __restrict__ s2d)
{
    const int tid = threadIdx.x, w = tid >> 6, l = tid & 63;
    const int lr = l & 15, lq = l >> 4;
    const int r0 = blockIdx.x * 64 + w * 16;

    const unsigned short* Bp = h1c + (size_t)(r0 + lr) * 256 + lq * 8;

    f4v acc[4] = {};
    #pragma unroll
    for (int ks = 0; ks < 8; ks++) {
        s8v bfrag = *(const s8v*)(Bp + ks * 32);
        #pragma unroll
        for (int dm = 0; dm < 4; dm++) {
            s8v a = *(const s8v*)(W2T + ((size_t)(dm * 16 + lr)) * 256 + lq * 8 + ks * 32);
            acc[dm] = __builtin_amdgcn_mfma_f32_16x16x32_bf16(a, bfrag, acc[dm], 0, 0, 0);
        }
    }

    const int node = r0 + lr;
    float ps = 0.f, pd = 0.f;
    #pragma unroll
    for (int dm = 0; dm < 4; dm++) {
        const int d0 = dm * 16 + lq * 4;
        float4 bi = *(const float4*)(b2 + d0);
        float4 as = *(const float4*)(a2 + d0);
        float4 ad = *(const float4*)(a2 + 64 + d0);
        ushort4 st; float vv;
        vv = acc[dm][0] + bi.x; st.x = f2bf(vv); ps = fmaf(vv, as.x, ps); pd = fmaf(vv, ad.x, pd);
        vv = acc[dm][1] + bi.y; st.y = f2bf(vv); ps = fmaf(vv, as.y, ps); pd = fmaf(vv, ad.y, pd);
        vv = acc[dm][2] + bi.z; st.z = f2bf(vv); ps = fmaf(vv, as.z, ps); pd = fmaf(vv, ad.z, pd);
        vv = acc[dm][3] + bi.w; st.w = f2bf(vv); ps = fmaf(vv, as.w, ps); pd = fmaf(vv, ad.w, pd);
        *(ushort4*)(z2c + (size_t)node * 64 + d0) = st;
    }
    ps += __shfl_xor(ps, 16); ps += __shfl_xor(ps, 32);
    pd += __shfl_xor(pd, 16); pd += __shfl_xor(pd, 32);
    if (lq == 0) { s2s[node] = f2bf(ps); s2d[node] = f2bf(pd); }
}

// ---------------- gi GEMM -> node-blocked gib2[b][n][c][t] ----------------
__global__ __launch_bounds__(256) void k_mgi(
    const unsigned short* __restrict__ h2b, const unsigned short* __restrict__ WihB,
    const float* __restrict__ bih, unsigned short* __restrict__ gib2)
{
    const int tid = threadIdx.x, w = tid >> 6, l = tid & 63;
    const int lr = l & 15, lq = l >> 4;
    const int r0 = blockIdx.x * 64 + w * 16;
    const int col0 = blockIdx.y * 64;

    const int rA = r0 + lr;
    const int bA = rA / 16000;
    const int remA = rA - bA * 16000;
    const int nAr = remA >> 3, tA = remA & 7;
    const unsigned short* Ab = h2b + ((size_t)((bA * 8 + tA) * 2000) + nAr) * 64 + lq * 8;

    f4v acc[4] = {};
    #pragma unroll
    for (int ks = 0; ks < 2; ks++) {
        s8v a = *(const s8v*)(Ab + ks * 32);
        #pragma unroll
        for (int nt = 0; nt < 4; nt++) {
            s8v bfr = *(const s8v*)(WihB + ((size_t)(col0 + nt * 16 + lr)) * 64 + lq * 8 + ks * 32);
            acc[nt] = __builtin_amdgcn_mfma_f32_16x16x32_bf16(a, bfr, acc[nt], 0, 0, 0);
        }
    }
    const int rrb = r0 + lq * 4;
    const int bO = rrb / 16000;
    const int remO = rrb - bO * 16000;
    const int nO = remO >> 3, tO = remO & 7;
    #pragma unroll
    for (int nt = 0; nt < 4; nt++) {
        int cc = col0 + nt * 16 + lr;
        float bias = bih[cc];
        ushort4 st;
        st.x = f2bf(acc[nt][0] + bias); st.y = f2bf(acc[nt][1] + bias);
        st.z = f2bf(acc[nt][2] + bias); st.w = f2bf(acc[nt][3] + bias);
        *(ushort4*)(gib2 + (((size_t)(bO * 2000 + nO)) * 192 + cc) * 8 + tO) = st;
    }
}

// ---------------- fused edge-softmax + aggregation + ELU, 8 rows/wave, wide gathers ----------------
__global__ void k_agg(const unsigned short* __restrict__ z, const unsigned short* __restrict__ ssrc,
                      const unsigned short* __restrict__ sdst, const float* __restrict__ ab,
                      const int* __restrict__ src, unsigned short* __restrict__ out,
                      int Hn, int outStride)
{
    const int blk = (blockIdx.x & 7) * ((int)gridDim.x >> 3) + (blockIdx.x >> 3);
    const int wv = threadIdx.x >> 6, lane = threadIdx.x & 63;
    const int rbase = blk * 32 + wv * 8;            // 8 rows, same bth (2000%8==0)
    const int bth = rbase / 2000;
    const int n0 = rbase - bth * 2000;
    const size_t zb = (size_t)bth * 2000;
    const int h = bth % Hn;

    // ---- phase 1: per-edge softmax (one edge per lane) ----
    const int rw_ = lane >> 3, k_ = lane & 7;
    const int sidx = src[(n0 + rw_) * 8 + k_];                 // coalesced dword
    float e = bf2f(ssrc[zb + sidx]) + bf2f(sdst[rbase + rw_]) + ab[h];
    e = e > 0.f ? e : 0.01f * e;                               // leaky_relu
    float m = e;
    m = fmaxf(m, __shfl_xor(m, 1)); m = fmaxf(m, __shfl_xor(m, 2)); m = fmaxf(m, __shfl_xor(m, 4));
    float ex = __expf(e - m);
    float sm = ex;
    sm += __shfl_xor(sm, 1); sm += __shfl_xor(sm, 2); sm += __shfl_xor(sm, 4);
    const float al = ex / sm;

    // ---- phase 2: wide gathers. lane = rw*8 + sub ----
    const int sub = lane & 7;                       // d-chunk within the row
    const int base8 = lane & 56;                    // rw*8
    float acc[8] = {0.f, 0.f, 0.f, 0.f, 0.f, 0.f, 0.f, 0.f};
    #pragma unroll
    for (int k = 0; k < 8; k++) {
        int row = __shfl(sidx, base8 | k);          // this rw's k-th neighbor
        float a_b = __shfl(al, base8 | k);
        u8v zv = *(const u8v*)(z + (zb + row) * 64 + sub * 8);   // 16B/lane, 8 rows/instr
        #pragma unroll
        for (int j = 0; j < 8; j++)
            acc[j] = fmaf(a_b, bf2f((unsigned short)zv[j]), acc[j]);
    }
    u8v ov;
    #pragma unroll
    for (int j = 0; j < 8; j++) {
        float v = acc[j];
        v = v > 0.f ? v : (__expf(v) - 1.f);        // ELU
        ov[j] = f2bf(v);
    }
    const int btl = bth / Hn;
    const int rw2 = lane >> 3;
    *(u8v*)(out + ((size_t)btl * N_ + n0 + rw2) * outStride + h * 64 + sub * 8) = ov;
}

// ---------------- MFMA GRU: 250 blocks, TWO chain-groups, warm 2 nodes ----------------
__global__ __launch_bounds__(256) void k_gru(
    const unsigned short* __restrict__ gib2, const unsigned short* __restrict__ WhhB,
    const float* __restrict__ bhh, const float* __restrict__ h0,
    float* __restrict__ hloc)
{
    const int q = blockIdx.x;                 // [0,250)
    const int tid = threadIdx.x;
    const int w = tid >> 6, l = tid & 63;
    const int lr = l & 15, lq = l >> 4;
    const int j0 = w * 16 + lq * 4;
    const int bb = lr & 7;                    // batch
    const int grp = lr >> 3;                  // chain group 0/1
    const int Q = q + grp * 250;              // chain id [0,500)

    __shared__ unsigned short hbuf[3][16][72];
    {
        unsigned int* p = (unsigned int*)hbuf;
        #pragma unroll 1
        for (int i = tid; i < 3 * 16 * 72 / 2; i += 256) p[i] = 0u;
    }
    __syncthreads();

    const int jrow = w * 16 + lr;
    s8v wR0 = *(const s8v*)(WhhB + (size_t)jrow * 64 + lq * 8);
    s8v wR1 = *(const s8v*)(WhhB + (size_t)jrow * 64 + 32 + lq * 8);
    s8v wZ0 = *(const s8v*)(WhhB + (size_t)(64 + jrow) * 64 + lq * 8);
    s8v wZ1 = *(const s8v*)(WhhB + (size_t)(64 + jrow) * 64 + 32 + lq * 8);
    s8v wN0 = *(const s8v*)(WhhB + (size_t)(128 + jrow) * 64 + lq * 8);
    s8v wN1 = *(const s8v*)(WhhB + (size_t)(128 + jrow) * 64 + 32 + lq * 8);

    float4 t4;
    t4 = *(const float4*)(bhh + j0);        float bhr_[4] = {t4.x, t4.y, t4.z, t4.w};
    t4 = *(const float4*)(bhh + 64 + j0);   float bhz_[4] = {t4.x, t4.y, t4.z, t4.w};
    t4 = *(const float4*)(bhh + 128 + j0);  float bhn_[4] = {t4.x, t4.y, t4.z, t4.w};

    float hp[4] = {0.f, 0.f, 0.f, 0.f};
    if (Q == 0) {
        float4 h04 = *(const float4*)(h0 + bb * 64 + j0);
        hp[0] = h04.x; hp[1] = h04.y; hp[2] = h04.z; hp[3] = h04.w;
        ushort4 st;
        st.x = f2bf(hp[0]); st.y = f2bf(hp[1]); st.z = f2bf(hp[2]); st.w = f2bf(hp[3]);
        *(ushort4*)&hbuf[0][lr][j0] = st;
    }
    __syncthreads();

    const unsigned short* gbase = gib2 + ((size_t)bb * 2000) * 192 * 8;
    const int ndF = Q * 4 - 2;                // warm 2 nodes (16 steps)

    int ndc = ndF < 0 ? 0 : ndF;
    u8v cRv[4], cZv[4], cNv[4];
    #pragma unroll
    for (int rg = 0; rg < 4; rg++) {
        cRv[rg] = *(const u8v*)(gbase + (((size_t)ndc * 192 + j0 + rg)) * 8);
        cZv[rg] = *(const u8v*)(gbase + (((size_t)ndc * 192 + 64 + j0 + rg)) * 8);
        cNv[rg] = *(const u8v*)(gbase + (((size_t)ndc * 192 + 128 + j0 + rg)) * 8);
    }

    int sb = 0;
    for (int o = 0; o < 6; ++o) {
        const int nd = ndF + o;
        u8v nRv[4] = {}, nZv[4] = {}, nNv[4] = {};
        if (o < 5) {
            int ndn = nd + 1; if (ndn < 0) ndn = 0;
            #pragma unroll
            for (int rg = 0; rg < 4; rg++) {
                nRv[rg] = *(const u8v*)(gbase + (((size_t)ndn * 192 + j0 + rg)) * 8);
                nZv[rg] = *(const u8v*)(gbase + (((size_t)ndn * 192 + 64 + j0 + rg)) * 8);
                nNv[rg] = *(const u8v*)(gbase + (((size_t)ndn * 192 + 128 + j0 + rg)) * 8);
            }
        }
        #pragma unroll
        for (int ts = 0; ts < 8; ts++) {
            const unsigned short* hbp = &hbuf[sb][lr][0];
            s8v hb0 = *(const s8v*)(hbp + lq * 8);
            s8v hb1 = *(const s8v*)(hbp + 32 + lq * 8);

            f4v aR = {}, aZ = {}, aN = {};
            aR = __builtin_amdgcn_mfma_f32_16x16x32_bf16(wR0, hb0, aR, 0, 0, 0);
            aR = __builtin_amdgcn_mfma_f32_16x16x32_bf16(wR1, hb1, aR, 0, 0, 0);
            aZ = __builtin_amdgcn_mfma_f32_16x16x32_bf16(wZ0, hb0, aZ, 0, 0, 0);
            aZ = __builtin_amdgcn_mfma_f32_16x16x32_bf16(wZ1, hb1, aZ, 0, 0, 0);
            aN = __builtin_amdgcn_mfma_f32_16x16x32_bf16(wN0, hb0, aN, 0, 0, 0);
            aN = __builtin_amdgcn_mfma_f32_16x16x32_bf16(wN1, hb1, aN, 0, 0, 0);

            #pragma unroll
            for (int rg = 0; rg < 4; rg++) {
                float gr = bf2f((unsigned short)cRv[rg][ts]);
                float gz = bf2f((unsigned short)cZv[rg][ts]);
                float gn = bf2f((unsigned short)cNv[rg][ts]);
                float rr = 1.f / (1.f + __expf(-(gr + aR[rg] + bhr_[rg])));
                float zz = 1.f / (1.f + __expf(-(gz + aZ[rg] + bhz_[rg])));
                float tn = gn + rr * (aN[rg] + bhn_[rg]);
                float nn = 1.f - 2.f / (__expf(2.f * tn) + 1.f);
                float hnew = (1.f - zz) * nn + zz * hp[rg];
                hp[rg] = (nd >= 0) ? hnew : hp[rg];
            }

            int nsb = sb + 1; if (nsb == 3) nsb = 0;
            ushort4 st;
            st.x = f2bf(hp[0]); st.y = f2bf(hp[1]);
            st.z = f2bf(hp[2]); st.w = f2bf(hp[3]);
            *(ushort4*)&hbuf[nsb][lr][j0] = st;
            if (ts == 7 && o >= 2) {
                float4 ov; ov.x = hp[0]; ov.y = hp[1]; ov.z = hp[2]; ov.w = hp[3];
                *(float4*)(hloc + ((size_t)nd * 8 + bb) * 64 + j0) = ov;
            }
            __syncthreads();
            sb = nsb;
        }
        #pragma unroll
        for (int rg = 0; rg < 4; rg++) {
            cRv[rg] = nRv[rg]; cZv[rg] = nZv[rg]; cNv[rg] = nNv[rg];
        }
    }
}

// ---------------- final projection ----------------
__global__ void k_proj(const float* __restrict__ hloc, const float* __restrict__ Wp,
                       const float* __restrict__ bp, float* __restrict__ out)
{
    int idx = blockIdx.x * 256 + threadIdx.x;   // 256000 total
    int p = idx & 15;
    int b = (idx >> 4) & 7;
    int n = idx >> 7;
    const float* hr = hloc + ((size_t)n * B_ + b) * 64;
    float acc = bp[p];
    #pragma unroll
    for (int jj = 0; jj < 64; jj++) acc = fmaf(hr[jj], Wp[jj * 16 + p], acc);
    out[((size_t)b * N_ + n) * PW_ + p] = acc;
}

extern "C" void kernel_launch(void* const* d_in, const int* in_sizes, int n_in,
                              void* d_out, int out_size, void* d_ws, size_t ws_size,
                              hipStream_t stream) {
    const float* dyn  = (const float*)d_in[0];
    const float* h0   = (const float*)d_in[1];
    const int*   src  = (const int*)  d_in[2];
    const float* W1   = (const float*)d_in[3];
    const float* b1   = (const float*)d_in[4];
    const float* a1   = (const float*)d_in[5];
    const float* a1b  = (const float*)d_in[6];
    const float* W2   = (const float*)d_in[7];
    const float* b2   = (const float*)d_in[8];
    const float* a2   = (const float*)d_in[9];
    const float* a2b  = (const float*)d_in[10];
    const float* Wih  = (const float*)d_in[11];
    const float* Whh  = (const float*)d_in[12];
    const float* bih  = (const float*)d_in[13];
    const float* bhh  = (const float*)d_in[14];
    const float* Wp   = (const float*)d_in[15];
    const float* bp   = (const float*)d_in[16];
    float* out = (float*)d_out;

    // Workspace: R7-proven layout, peak 133,267,456 B.
    char* w = (char*)d_ws;
    unsigned short* z1c  = (unsigned short*)(w);                  // 65,536,000
    unsigned short* h1c  = (unsigned short*)(w + 65536000);       // 65,536,000
    unsigned short* s1s  = (unsigned short*)(w + 131072000);      //  1,024,000 (bf16)
    unsigned short* s1d  = (unsigned short*)(w + 132096000);      //  1,024,000
    unsigned short* W1T  = (unsigned short*)(w + 133120000);      //     65,536
    unsigned short* W2T  = (unsigned short*)(w + 133185536);      //     32,768
    unsigned short* WihB = (unsigned short*)(w + 133218304);      //     24,576
    unsigned short* WhhB = (unsigned short*)(w + 133242880);      //     24,576 -> 133,267,456
    unsigned short* z2c  = (unsigned short*)(w);                  // 16,384,000 (over dead z1c)
    unsigned short* s2s  = (unsigned short*)(w + 16384000);       //    256,000
    unsigned short* s2d  = (unsigned short*)(w + 16640000);       //    256,000
    unsigned short* h2b  = (unsigned short*)(w + 16896000);       // 16,384,000
    float*          hloc = (float*)        (w + 33280000);        //  4,096,000
    unsigned short* gib2 = (unsigned short*)(w + 65536000);       // 49,152,000 (over dead h1c)

    k_cvt_w<<<288, 256, 0, stream>>>(W1, W2, Wih, Whh, W1T, W2T, WihB, WhhB);

    // Single-chunk GAT pipeline
    k_mz1<<<1000, 256, 0, stream>>>(dyn, W1T, b1, a1, z1c, s1s, s1d);
    k_agg<<<16000, 256, 0, stream>>>(z1c, s1s, s1d, a1b, src, h1c, H_, 256);
    k_mz2<<<2000, 256, 0, stream>>>(h1c, W2T, b2, a2, z2c, s2s, s2d);
    k_agg<<<4000, 256, 0, stream>>>(z2c, s2s, s2d, a2b, src, h2b, 1, 64);

    k_mgi<<<dim3(2000, 3), 256, 0, stream>>>(h2b, WihB, bih, gib2);
    k_gru<<<250, 256, 0, stream>>>(gib2, WhhB, bhh, h0, hloc);
    k_proj<<<1000, 256, 0, stream>>>(hloc, Wp, bp, out);
}